// Round 10
// baseline (183.044 us; speedup 1.0000x reference)
//
#include <hip/hip_runtime.h>
#include <hip/hip_bf16.h>
#include <hip/hip_fp16.h>
#include <math.h>

// AutoCorrelation (Autoformer). B=16, L=2048, H=8, E=64, fp32.
// Round 10: out-of-core split to make ALL HBM touches DRAM-contiguous.
//  pack: reads full 2KB rows (64KB contiguous per block per input), writes
//        64KB contiguous fp16 slabs z[b][tile][cq][j][u] (u = channel in quad).
//  fft:  8 ch/block staged from 1KB-contiguous slab chunks; FFT/product
//        machinery identical to validated r9 (2 halves x 2 passes, fp16 LDS
//        spectra, fp32 register math, digit-reversed storage).
// part fp32 [1024][2048]; ifft sums 64 rows; topk/aggregate unchanged.

#define B_ 16
#define L_ 2048
#define H_ 8
#define E_ 64
#define K_ 7
#define RS_ 2178          // fft region stride in 4B words (2178 % 32 == 2)

// ---------- workspace layout ----------
#define Z_OFF    0ull                              // fp16 slabs: 1024 x 64KB = 64 MiB
#define PART_OFF 67108864ull                       // float2[1024][2048] = 16 MiB
#define MV_OFF   (PART_OFF + 16777216ull)          // float [B][L]
#define TK_OFF   (MV_OFF + 131072ull)              // int[7]
#define W_OFF    (TK_OFF + 64ull)                  // float[16][7]

// ---------- complex helpers ----------
__device__ __forceinline__ float2 cadd(float2 a, float2 b) { return make_float2(a.x + b.x, a.y + b.y); }
__device__ __forceinline__ float2 csub(float2 a, float2 b) { return make_float2(a.x - b.x, a.y - b.y); }
__device__ __forceinline__ float2 cmul(float2 a, float2 b) {
  return make_float2(fmaf(a.x, b.x, -a.y * b.y), fmaf(a.x, b.y, a.y * b.x));
}
__device__ __forceinline__ float2 cis(float ang) { float s, c; sincosf(ang, &s, &c); return make_float2(c, s); }

template<int S> __device__ __forceinline__ float2 rot90(float2 z) {  // *W_4^{S}: S=-1 -> -i*z
  return (S < 0) ? make_float2(z.y, -z.x) : make_float2(-z.y, z.x);
}
template<int S> __device__ __forceinline__ void dft4(float2& a, float2& b, float2& c, float2& d) {
  float2 t0 = cadd(a, c), t1 = csub(a, c), t2 = cadd(b, d), t3 = rot90<S>(csub(b, d));
  a = cadd(t0, t2); c = csub(t0, t2); b = cadd(t1, t3); d = csub(t1, t3);
}
template<int S> __device__ __forceinline__ void dft8(float2 v[8]) {
  const float RT = 0.70710678118654752f;
  const float SR = (S < 0) ? -RT : RT;
  float2 a0 = cadd(v[0], v[4]), a1 = cadd(v[1], v[5]), a2 = cadd(v[2], v[6]), a3 = cadd(v[3], v[7]);
  float2 b0 = csub(v[0], v[4]), b1 = csub(v[1], v[5]), b2 = csub(v[2], v[6]), b3 = csub(v[3], v[7]);
  b1 = cmul(b1, make_float2(RT, SR));     // W8^{S}
  b2 = rot90<S>(b2);                      // W8^{2S}
  b3 = cmul(b3, make_float2(-RT, SR));    // W8^{3S}
  dft4<S>(a0, a1, a2, a3);
  dft4<S>(b0, b1, b2, b3);
  v[0] = a0; v[2] = a1; v[4] = a2; v[6] = a3;
  v[1] = b0; v[3] = b1; v[5] = b2; v[7] = b3;
}
// padded in-region index: +1 word per 16 (<=2-way across all stage patterns)
__device__ __forceinline__ int sg(int e) { return e + (e >> 4); }

__device__ __forceinline__ float2 ld16(const __half2* p) { return __half22float2(*p); }
__device__ __forceinline__ void st16(__half2* p, float2 v) { *p = __float22half2_rn(v); }

// ---------- kernel P: row-sequential pack q,k -> fp16 slabs ----------
// Block (b, tile): reads 32 full 2KB rows of q and k (fully sequential),
// writes one 64KB contiguous slab. Slab micro-layout: float4 at (cq, j) holds
// half2(q,k) for channels 4cq+u (u=0..3) at tau = tile*32 + j.
__global__ __launch_bounds__(512) void pack_kernel(
    const float* __restrict__ q, const float* __restrict__ k,
    float4* __restrict__ z) {
  extern __shared__ float4 tile[];        // [128][33] = 4224 f4 = 67584 B
  int tid = threadIdx.x;
  int l = blockIdx.x;                     // b*64 + tileIdx
  int tl = l & 63, b = l >> 6;
  size_t rowbase = ((size_t)b * L_ + tl * 32) * 512;   // floats
  const float4* q4 = (const float4*)(q + rowbase);
  const float4* k4 = (const float4*)(k + rowbase);
#pragma unroll
  for (int pass = 0; pass < 8; ++pass) {
    int m = pass * 512 + tid;
    int j = m >> 7, cq = m & 127;         // j = tau-in-tile, cq = channel quad
    float4 qv = q4[j * 128 + cq];
    float4 kv = k4[j * 128 + cq];
    float4 pk;
    ((__half2*)&pk)[0] = __float22half2_rn(make_float2(qv.x, kv.x));
    ((__half2*)&pk)[1] = __float22half2_rn(make_float2(qv.y, kv.y));
    ((__half2*)&pk)[2] = __float22half2_rn(make_float2(qv.z, kv.z));
    ((__half2*)&pk)[3] = __float22half2_rn(make_float2(qv.w, kv.w));
    tile[cq * 33 + j] = pk;
  }
  __syncthreads();
  float4* slab = z + (size_t)l * 4096;    // 4096 f4 = 64KB contiguous
#pragma unroll
  for (int pass = 0; pass < 8; ++pass) {
    int m = pass * 512 + tid;
    int cq = m >> 5, j = m & 31;
    slab[cq * 32 + j] = tile[cq * 33 + j];
  }
}

// ---------- kernel F: slab-read + radix-8/8/8/4 DIF FFT + freq product ----------
// Block: 8 channels (2 cq-quads), 512 threads, 8 fp16 LDS regions, 2 passes x
// 2 halves (r9-validated structure). Staging reads 1KB-contiguous slab chunks.
// Digit-reversed storage pos = 256k1+32k2+4k3+k4, frequency f = k1+8k2+64k3+512k4.
__global__ __launch_bounds__(512) void fft_corr_kernel(
    const float4* __restrict__ z, float2* __restrict__ part) {
  extern __shared__ __half2 dbuf[];       // 8 regions x RS_ words = 69696 B
  int tid = threadIdx.x;
  int t = tid & 255;                      // lane within half
  int half = tid >> 8;
  int j2 = t & 31, j3 = t & 3;
  int l = blockIdx.x;                     // b*64 + cg
  int cg = l & 63, b = l >> 6;
  int cq0 = cg * 2;                       // channels 8cg .. 8cg+7
  const float4* zb = z + (size_t)b * 64 * 4096;

  // ---- staging: per tile read 2 cq-quads x 32 j = 1KB contiguous
#pragma unroll
  for (int it = 0; it < 8; ++it) {
    int m = it * 512 + tid;
    int tl = m >> 6, inner = m & 63;
    int cqr = inner >> 5, j = inner & 31;
    float4 pk = zb[(size_t)tl * 4096 + (cq0 + cqr) * 32 + j];
    int sp = sg(tl * 32 + j);
    const __half2* hp = (const __half2*)&pk;
    dbuf[(cqr * 4 + 0) * RS_ + sp] = hp[0];
    dbuf[(cqr * 4 + 1) * RS_ + sp] = hp[1];
    dbuf[(cqr * 4 + 2) * RS_ + sp] = hp[2];
    dbuf[(cqr * 4 + 3) * RS_ + sp] = hp[3];
  }
  __syncthreads();                        // all 8 regions staged

  // twiddles (t-dependent, shared by both passes)
  float2 tw1[7], tw2[7], tw3[7];
  {
    float2 w1 = cis(-6.283185307179586f * (float)t  / 2048.0f);
    float2 w2 = cis(-6.283185307179586f * (float)j2 / 256.0f);
    float2 w3 = cis(-6.283185307179586f * (float)j3 / 32.0f);
    tw1[0] = w1; tw2[0] = w2; tw3[0] = w3;
#pragma unroll
    for (int kk = 1; kk < 7; ++kk) {
      tw1[kk] = cmul(tw1[kk - 1], w1);
      tw2[kk] = cmul(tw2[kk - 1], w2);
      tw3[kk] = cmul(tw3[kk - 1], w3);
    }
  }
  int base2 = (t >> 5) * 256 + j2;
  int base3 = (t >> 2) * 32 + j3;
  float2 acc[8];
#pragma unroll
  for (int kk = 0; kk < 8; ++kk) acc[kk] = make_float2(0.f, 0.f);

  for (int p = 0; p < 2; ++p) {
    __half2* A  = dbuf + (size_t)(4 * p + 2 * half) * RS_;
    __half2* Bf = A + RS_;
    float2 va[8], vb[8];
    // ---- stage 1 (M=2048), in-place (read set == write set per thread)
#pragma unroll
    for (int m = 0; m < 8; ++m) { va[m] = ld16(&A[sg(t + 256 * m)]); vb[m] = ld16(&Bf[sg(t + 256 * m)]); }
    dft8<-1>(va); dft8<-1>(vb);
#pragma unroll
    for (int kk = 1; kk < 8; ++kk) { va[kk] = cmul(va[kk], tw1[kk - 1]); vb[kk] = cmul(vb[kk], tw1[kk - 1]); }
#pragma unroll
    for (int kk = 0; kk < 8; ++kk) { st16(&A[sg(t + 256 * kk)], va[kk]); st16(&Bf[sg(t + 256 * kk)], vb[kk]); }
    __syncthreads();
    // ---- stage 2 (M=256)
#pragma unroll
    for (int m = 0; m < 8; ++m) { va[m] = ld16(&A[sg(base2 + 32 * m)]); vb[m] = ld16(&Bf[sg(base2 + 32 * m)]); }
    dft8<-1>(va); dft8<-1>(vb);
#pragma unroll
    for (int kk = 1; kk < 8; ++kk) { va[kk] = cmul(va[kk], tw2[kk - 1]); vb[kk] = cmul(vb[kk], tw2[kk - 1]); }
#pragma unroll
    for (int kk = 0; kk < 8; ++kk) { st16(&A[sg(base2 + 32 * kk)], va[kk]); st16(&Bf[sg(base2 + 32 * kk)], vb[kk]); }
    __syncthreads();
    // ---- stage 3 (M=32)
#pragma unroll
    for (int m = 0; m < 8; ++m) { va[m] = ld16(&A[sg(base3 + 4 * m)]); vb[m] = ld16(&Bf[sg(base3 + 4 * m)]); }
    dft8<-1>(va); dft8<-1>(vb);
#pragma unroll
    for (int kk = 1; kk < 8; ++kk) { va[kk] = cmul(va[kk], tw3[kk - 1]); vb[kk] = cmul(vb[kk], tw3[kk - 1]); }
#pragma unroll
    for (int kk = 0; kk < 8; ++kk) { st16(&A[sg(base3 + 4 * kk)], va[kk]); st16(&Bf[sg(base3 + 4 * kk)], vb[kk]); }
    __syncthreads();
    // ---- stage 4 (M=4 radix-4, thread-private quads)
#pragma unroll
    for (int kk = 0; kk < 8; ++kk) { va[kk] = ld16(&A[sg(8 * t + kk)]); vb[kk] = ld16(&Bf[sg(8 * t + kk)]); }
    dft4<-1>(va[0], va[1], va[2], va[3]); dft4<-1>(va[4], va[5], va[6], va[7]);
    dft4<-1>(vb[0], vb[1], vb[2], vb[3]); dft4<-1>(vb[4], vb[5], vb[6], vb[7]);
#pragma unroll
    for (int kk = 0; kk < 8; ++kk) { st16(&A[sg(8 * t + kk)], va[kk]); st16(&Bf[sg(8 * t + kk)], vb[kk]); }
    __syncthreads();
    // ---- product: P = Qf*conj(Kf), -f by digit arithmetic; accumulate.
    // (next pass touches DIFFERENT regions -> no trailing barrier needed)
#pragma unroll
    for (int kk = 0; kk < 8; ++kk) {
      int pos = 8 * t + kk;
      int f  = ((pos >> 8) & 7) | (((pos >> 5) & 7) << 3) | (((pos >> 2) & 7) << 6) | ((pos & 3) << 9);
      int fp = (2048 - f) & 2047;
      int pp = ((fp & 7) << 8) | (((fp >> 3) & 7) << 5) | (((fp >> 6) & 7) << 2) | ((fp >> 9) & 3);
      float2 Ax = va[kk], Bc = ld16(&A[sg(pp)]);
      acc[kk].x += 0.5f  * (Bc.x * Ax.y + Bc.y * Ax.x);
      acc[kk].y += 0.25f * (Ax.x * Ax.x + Ax.y * Ax.y - Bc.x * Bc.x - Bc.y * Bc.y);
      Ax = vb[kk]; Bc = ld16(&Bf[sg(pp)]);
      acc[kk].x += 0.5f  * (Bc.x * Ax.y + Bc.y * Ax.x);
      acc[kk].y += 0.25f * (Ax.x * Ax.x + Ax.y * Ax.y - Bc.x * Bc.x - Bc.y * Bc.y);
    }
  }
  // park per-half sums FP32: half 0 -> planes 0(re),1(im); half 1 -> 2,3.
  // Regions 0-3 are dead (pass-0 product reads completed before pass-1's
  // first barrier). fp32 because |P| summed over channels exceeds fp16 range.
  {
    float* fre = (float*)dbuf + (size_t)(2 * half) * RS_;
    float* fim = fre + RS_;
#pragma unroll
    for (int kk = 0; kk < 8; ++kk) {
      int sp = sg(8 * t + kk);
      fre[sp] = acc[kk].x;
      fim[sp] = acc[kk].y;
    }
  }
  __syncthreads();
  // cross-half sum + coalesced 512-wide store
  {
    const float* r0 = (const float*)dbuf;
    const float* i0 = r0 + RS_;
    const float* r1 = r0 + 2 * RS_;
    const float* i1 = r0 + 3 * RS_;
    float2* prow = part + (size_t)l * L_;
#pragma unroll
    for (int m = 0; m < 4; ++m) {
      int p = tid + 512 * m;
      int sp = sg(p);
      prow[p] = make_float2(r0[sp] + r1[sp], i0[sp] + i1[sp]);
    }
  }
}

// ---------- kernel I: sum 64 partial rows + mirrored DIT inverse ----------
__global__ __launch_bounds__(256) void ifft_kernel(
    const float2* __restrict__ part, float* __restrict__ mv) {
  __shared__ float2 buf[2176];
  int t = threadIdx.x, b = blockIdx.x;
  int j2 = t & 31, j3 = t & 3;
  float2 tw1[7], tw2[7], tw3[7];
  {
    float2 w1 = cis(6.283185307179586f * (float)t  / 2048.0f);
    float2 w2 = cis(6.283185307179586f * (float)j2 / 256.0f);
    float2 w3 = cis(6.283185307179586f * (float)j3 / 32.0f);
    tw1[0] = w1; tw2[0] = w2; tw3[0] = w3;
#pragma unroll
    for (int kk = 1; kk < 7; ++kk) {
      tw1[kk] = cmul(tw1[kk - 1], w1);
      tw2[kk] = cmul(tw2[kk - 1], w2);
      tw3[kk] = cmul(tw3[kk - 1], w3);
    }
  }
  int base2 = (t >> 5) * 256 + j2;
  int base3 = (t >> 2) * 32 + j3;
  // stage A: 64-row reduction + M=4 DFT (no twiddle), quads 8t..8t+7
  float2 u[8];
#pragma unroll
  for (int kk = 0; kk < 8; ++kk) u[kk] = make_float2(0.f, 0.f);
#pragma unroll 4
  for (int g = 0; g < 64; ++g) {
    const float4* rp = (const float4*)(part + (size_t)(b * 64 + g) * L_);
#pragma unroll
    for (int m = 0; m < 4; ++m) {
      float4 f = rp[4 * t + m];
      u[2 * m].x     += f.x; u[2 * m].y     += f.y;
      u[2 * m + 1].x += f.z; u[2 * m + 1].y += f.w;
    }
  }
  dft4<1>(u[0], u[1], u[2], u[3]);
  dft4<1>(u[4], u[5], u[6], u[7]);
#pragma unroll
  for (int kk = 0; kk < 8; ++kk) buf[sg(8 * t + kk)] = u[kk];
  __syncthreads();
  // stage B: M=32 (twiddle inputs, then inverse DFT)
  float2 v[8];
#pragma unroll
  for (int kk = 0; kk < 8; ++kk) v[kk] = buf[sg(base3 + 4 * kk)];
#pragma unroll
  for (int kk = 1; kk < 8; ++kk) v[kk] = cmul(v[kk], tw3[kk - 1]);
  dft8<1>(v);
  __syncthreads();
#pragma unroll
  for (int m = 0; m < 8; ++m) buf[sg(base3 + 4 * m)] = v[m];
  __syncthreads();
  // stage C: M=256
#pragma unroll
  for (int kk = 0; kk < 8; ++kk) v[kk] = buf[sg(base2 + 32 * kk)];
#pragma unroll
  for (int kk = 1; kk < 8; ++kk) v[kk] = cmul(v[kk], tw2[kk - 1]);
  dft8<1>(v);
  __syncthreads();
#pragma unroll
  for (int m = 0; m < 8; ++m) buf[sg(base2 + 32 * m)] = v[m];
  __syncthreads();
  // stage D: M=2048 -> natural-order x[t+256m]
#pragma unroll
  for (int kk = 0; kk < 8; ++kk) v[kk] = buf[sg(t + 256 * kk)];
#pragma unroll
  for (int kk = 1; kk < 8; ++kk) v[kk] = cmul(v[kk], tw1[kk - 1]);
  dft8<1>(v);
  const float scale = 1.0f / (2048.0f * 512.0f);  // 1/N * mean over H*E
#pragma unroll
  for (int m = 0; m < 8; ++m) mv[b * L_ + t + 256 * m] = v[m].x * scale;
}

// ---------- kernel K: batch-mean top-7 + per-batch softmax weights ----------
__global__ __launch_bounds__(256) void topk_kernel(
    const float* __restrict__ mv, int* __restrict__ topk, float* __restrict__ wts) {
  __shared__ float av[2048];
  __shared__ float rv[256];
  __shared__ int   ri[256];
  __shared__ int   sidx[K_];
  int tid = threadIdx.x;
  for (int d = tid; d < 2048; d += 256) {
    float s = 0.f;
#pragma unroll
    for (int b = 0; b < B_; ++b) s += mv[b * L_ + d];
    av[d] = s;
  }
  __syncthreads();
  for (int kk = 0; kk < K_; ++kk) {
    float bv = -INFINITY; int bi = 0;
    for (int d = tid; d < 2048; d += 256) {
      float vv = av[d];
      if (vv > bv) { bv = vv; bi = d; }
    }
    rv[tid] = bv; ri[tid] = bi;
    __syncthreads();
    for (int off = 128; off > 0; off >>= 1) {
      if (tid < off) {
        float v2 = rv[tid + off]; int i2 = ri[tid + off];
        if (v2 > rv[tid] || (v2 == rv[tid] && i2 < ri[tid])) { rv[tid] = v2; ri[tid] = i2; }
      }
      __syncthreads();
    }
    if (tid == 0) { sidx[kk] = ri[0]; av[ri[0]] = -INFINITY; }
    __syncthreads();
  }
  if (tid < K_) topk[tid] = sidx[tid];
  if (tid < B_) {
    float xk[K_], m = -INFINITY;
#pragma unroll
    for (int kk = 0; kk < K_; ++kk) { xk[kk] = mv[tid * L_ + sidx[kk]]; m = fmaxf(m, xk[kk]); }
    float s = 0.f;
#pragma unroll
    for (int kk = 0; kk < K_; ++kk) { xk[kk] = expf(xk[kk] - m); s += xk[kk]; }
#pragma unroll
    for (int kk = 0; kk < K_; ++kk) wts[tid * K_ + kk] = xk[kk] / s;
  }
}

// ---------- kernel G: out[b,t,h,e] = sum_k w[b,k] * v[b,(t+d_k)%L,h,e] ----------
__global__ __launch_bounds__(256) void aggregate_kernel(
    const float4* __restrict__ v4, const int* __restrict__ topk,
    const float* __restrict__ wts, float4* __restrict__ out4) {
  __shared__ int   sidx[K_];
  __shared__ float sw[B_][K_];
  int tid = threadIdx.x;
  if (tid < K_) sidx[tid] = topk[tid];
  if (tid < B_ * K_) sw[tid / K_][tid % K_] = wts[tid];
  __syncthreads();
  int idx = blockIdx.x * 256 + tid;
  int c4  = idx & 127;
  int row = idx >> 7;
  int t   = row & (L_ - 1);
  int b   = row >> 11;
  float4 acc = make_float4(0.f, 0.f, 0.f, 0.f);
#pragma unroll
  for (int kk = 0; kk < K_; ++kk) {
    int s = t + sidx[kk];
    if (s >= L_) s -= L_;
    float w = sw[b][kk];
    float4 val = v4[((size_t)(b * L_ + s) << 7) + c4];
    acc.x += w * val.x; acc.y += w * val.y;
    acc.z += w * val.z; acc.w += w * val.w;
  }
  out4[idx] = acc;
}

extern "C" void kernel_launch(void* const* d_in, const int* in_sizes, int n_in,
                              void* d_out, int out_size, void* d_ws, size_t ws_size,
                              hipStream_t stream) {
  const float* q = (const float*)d_in[0];
  const float* k = (const float*)d_in[1];
  const float* v = (const float*)d_in[2];
  float* out = (float*)d_out;

  char* ws = (char*)d_ws;
  float4* z    = (float4*)(ws + Z_OFF);
  float2* part = (float2*)(ws + PART_OFF);
  float*  mv   = (float*) (ws + MV_OFF);
  int*    topk = (int*)   (ws + TK_OFF);
  float*  wts  = (float*) (ws + W_OFF);

  pack_kernel<<<B_ * 64, 512, 4224 * sizeof(float4), stream>>>(q, k, z);
  fft_corr_kernel<<<B_ * 64, 512, 8 * RS_ * 4, stream>>>(z, part);
  ifft_kernel<<<B_, 256, 0, stream>>>(part, mv);
  topk_kernel<<<1, 256, 0, stream>>>(mv, topk, wts);
  aggregate_kernel<<<(B_ * L_ * H_ * E_ / 4) / 256, 256, 0, stream>>>(
      (const float4*)v, topk, wts, (float4*)out);
}

// Round 11
// 159.827 us; speedup vs baseline: 1.1453x; 1.1453x over previous
//
#include <hip/hip_runtime.h>
#include <hip/hip_bf16.h>
#include <hip/hip_fp16.h>
#include <math.h>

// AutoCorrelation (Autoformer). B=16, L=2048, H=8, E=64, fp32.
// Round 11: packed-fp16 FFT. Channel PAIRS ride in __half2 lanes; all
// butterfly math is v_pk_* (2 channels/op). LDS holds {re,im} adjacent ->
// one ds_*_b64 per complex pair. 4 channels/block, 256 threads, 2048 blocks,
// 34.8KB LDS -> 4 blocks/CU (4 independent barrier domains). pack (r10,
// roofline-bound) unchanged except pair-packed slab grouping. Deterministic
// reduce kernel; ifft/topk/aggregate as validated.

#define B_ 16
#define L_ 2048
#define H_ 8
#define E_ 64
#define K_ 7
#define RS_ 2178          // region stride in uint2 (8B) units; sg(2047)=2174 < RS_

// ---------- workspace layout ----------
#define Z_OFF    0ull                              // fp16 slabs: 1024 x 64KB = 64 MiB
#define PART_OFF 67108864ull                       // float2[2048][2048] = 32 MiB
#define S_OFF    (PART_OFF + 33554432ull)          // float2[16][2048] = 256 KiB
#define MV_OFF   (S_OFF + 262144ull)               // float [B][L]
#define TK_OFF   (MV_OFF + 131072ull)              // int[7]
#define W_OFF    (TK_OFF + 64ull)                  // float[16][7]

// ---------- fp32 complex helpers (ifft/twiddle gen) ----------
__device__ __forceinline__ float2 cadd(float2 a, float2 b) { return make_float2(a.x + b.x, a.y + b.y); }
__device__ __forceinline__ float2 csub(float2 a, float2 b) { return make_float2(a.x - b.x, a.y - b.y); }
__device__ __forceinline__ float2 cmul(float2 a, float2 b) {
  return make_float2(fmaf(a.x, b.x, -a.y * b.y), fmaf(a.x, b.y, a.y * b.x));
}
__device__ __forceinline__ float2 cis(float ang) { float s, c; sincosf(ang, &s, &c); return make_float2(c, s); }

template<int S> __device__ __forceinline__ float2 rot90(float2 z) {
  return (S < 0) ? make_float2(z.y, -z.x) : make_float2(-z.y, z.x);
}
template<int S> __device__ __forceinline__ void dft4(float2& a, float2& b, float2& c, float2& d) {
  float2 t0 = cadd(a, c), t1 = csub(a, c), t2 = cadd(b, d), t3 = rot90<S>(csub(b, d));
  a = cadd(t0, t2); c = csub(t0, t2); b = cadd(t1, t3); d = csub(t1, t3);
}
template<int S> __device__ __forceinline__ void dft8(float2 v[8]) {
  const float RT = 0.70710678118654752f;
  const float SR = (S < 0) ? -RT : RT;
  float2 a0 = cadd(v[0], v[4]), a1 = cadd(v[1], v[5]), a2 = cadd(v[2], v[6]), a3 = cadd(v[3], v[7]);
  float2 b0 = csub(v[0], v[4]), b1 = csub(v[1], v[5]), b2 = csub(v[2], v[6]), b3 = csub(v[3], v[7]);
  b1 = cmul(b1, make_float2(RT, SR));
  b2 = rot90<S>(b2);
  b3 = cmul(b3, make_float2(-RT, SR));
  dft4<S>(a0, a1, a2, a3);
  dft4<S>(b0, b1, b2, b3);
  v[0] = a0; v[2] = a1; v[4] = a2; v[6] = a3;
  v[1] = b0; v[3] = b1; v[5] = b2; v[7] = b3;
}
// padded index: +1 element per 16 (<=2-way across all stage patterns)
__device__ __forceinline__ int sg(int e) { return e + (e >> 4); }

// ---------- packed-fp16 complex (channel pair per __half2 lane-slot) ----------
struct hc { __half2 re, im; };
__device__ __forceinline__ hc hcadd(hc a, hc b) { return { __hadd2(a.re, b.re), __hadd2(a.im, b.im) }; }
__device__ __forceinline__ hc hcsub(hc a, hc b) { return { __hsub2(a.re, b.re), __hsub2(a.im, b.im) }; }
template<int S> __device__ __forceinline__ hc hrot90(hc z) {       // *(-i) fwd
  hc r; if (S < 0) { r.re = z.im; r.im = __hneg2(z.re); } else { r.re = __hneg2(z.im); r.im = z.re; }
  return r;
}
__device__ __forceinline__ hc hcmul(hc v, __half2 wre, __half2 wim) {
  hc r;
  r.re = __hsub2(__hmul2(v.re, wre), __hmul2(v.im, wim));
  r.im = __hfma2(v.re, wim, __hmul2(v.im, wre));
  return r;
}
template<int S> __device__ __forceinline__ void hdft4(hc& a, hc& b, hc& c, hc& d) {
  hc t0 = hcadd(a, c), t1 = hcsub(a, c), t2 = hcadd(b, d), t3 = hrot90<S>(hcsub(b, d));
  a = hcadd(t0, t2); c = hcsub(t0, t2); b = hcadd(t1, t3); d = hcsub(t1, t3);
}
template<int S> __device__ __forceinline__ void hdft8(hc v[8]) {
  const float RT = 0.70710678118654752f;
  __half2 rt  = __float2half2_rn(RT);
  __half2 sr  = __float2half2_rn((S < 0) ? -RT : RT);
  __half2 nrt = __float2half2_rn(-RT);
  hc a0 = hcadd(v[0], v[4]), a1 = hcadd(v[1], v[5]), a2 = hcadd(v[2], v[6]), a3 = hcadd(v[3], v[7]);
  hc b0 = hcsub(v[0], v[4]), b1 = hcsub(v[1], v[5]), b2 = hcsub(v[2], v[6]), b3 = hcsub(v[3], v[7]);
  b1 = hcmul(b1, rt, sr);
  b2 = hrot90<S>(b2);
  b3 = hcmul(b3, nrt, sr);
  hdft4<S>(a0, a1, a2, a3);
  hdft4<S>(b0, b1, b2, b3);
  v[0] = a0; v[2] = a1; v[4] = a2; v[6] = a3;
  v[1] = b0; v[3] = b1; v[5] = b2; v[7] = b3;
}
__device__ __forceinline__ __half2 u2h(unsigned u) { return __builtin_bit_cast(__half2, u); }
__device__ __forceinline__ unsigned h2u(__half2 h) { return __builtin_bit_cast(unsigned, h); }

// ---------- kernel P: row-sequential pack q,k -> pair-packed fp16 slabs ----------
// Block (b,tile): reads 32 full 2KB rows of q,k (contiguous); writes one 64KB
// contiguous slab. f4 at (cq,j) = [re01,im01,re23,im23]: re01=h2(q_{4cq},q_{4cq+1}),
// im01=h2(k_{4cq},k_{4cq+1}), etc. (z = q + i*k per channel, pair-packed).
__global__ __launch_bounds__(512) void pack_kernel(
    const float* __restrict__ q, const float* __restrict__ k,
    float4* __restrict__ z) {
  extern __shared__ float4 tile[];        // [128][33] = 4224 f4 = 67584 B
  int tid = threadIdx.x;
  int l = blockIdx.x;                     // b*64 + tileIdx
  int tl = l & 63, b = l >> 6;
  size_t rowbase = ((size_t)b * L_ + tl * 32) * 512;
  const float4* q4 = (const float4*)(q + rowbase);
  const float4* k4 = (const float4*)(k + rowbase);
#pragma unroll
  for (int pass = 0; pass < 8; ++pass) {
    int m = pass * 512 + tid;
    int j = m >> 7, cq = m & 127;
    float4 qv = q4[j * 128 + cq];
    float4 kv = k4[j * 128 + cq];
    float4 pk;
    ((__half2*)&pk)[0] = __float22half2_rn(make_float2(qv.x, qv.y));  // re01
    ((__half2*)&pk)[1] = __float22half2_rn(make_float2(kv.x, kv.y));  // im01
    ((__half2*)&pk)[2] = __float22half2_rn(make_float2(qv.z, qv.w));  // re23
    ((__half2*)&pk)[3] = __float22half2_rn(make_float2(kv.z, kv.w));  // im23
    tile[cq * 33 + j] = pk;
  }
  __syncthreads();
  float4* slab = z + (size_t)l * 4096;
#pragma unroll
  for (int pass = 0; pass < 8; ++pass) {
    int m = pass * 512 + tid;
    int cq = m >> 5, j = m & 31;
    slab[cq * 32 + j] = tile[cq * 33 + j];
  }
}

// ---------- kernel F: packed-fp16 radix-8/8/8/4 DIF FFT + freq product ----------
// Block (b, cg): channels 4cg..4cg+3 as 2 packed pairs; 256 threads; 2 LDS
// regions of RS_ uint2 ({re,im} adjacent -> b64 ops). 2 passes, 4 barriers
// each, regions single-purpose. Digit-reversed storage pos=256k1+32k2+4k3+k4,
// f = k1+8k2+64k3+512k4.
__global__ __launch_bounds__(256) void fft_corr_kernel(
    const float4* __restrict__ z, float2* __restrict__ part) {
  extern __shared__ uint2 dbuf[];         // 2 regions x RS_ uint2 = 34848 B
  int t = threadIdx.x;
  int j2 = t & 31, j3 = t & 3;
  int l = blockIdx.x;                     // b*128 + cg
  int cg = l & 127, b = l >> 7;
  const float4* zb = z + (size_t)b * 64 * 4096;

  // ---- staging: 64 tiles x 32 j of cq=cg -> 512B contiguous runs
#pragma unroll
  for (int it = 0; it < 8; ++it) {
    int m = it * 256 + t;
    int tl = m >> 5, j = m & 31;
    float4 pk = zb[(size_t)tl * 4096 + cg * 32 + j];
    int sp = sg(tl * 32 + j);
    dbuf[sp]       = make_uint2(__float_as_uint(pk.x), __float_as_uint(pk.y));
    dbuf[RS_ + sp] = make_uint2(__float_as_uint(pk.z), __float_as_uint(pk.w));
  }

  // twiddles: fp32 iterative chains -> broadcast half2 (shared by both passes)
  __half2 t1re[7], t1im[7], t2re[7], t2im[7], t3re[7], t3im[7];
  {
    float2 w1 = cis(-6.283185307179586f * (float)t  / 2048.0f);
    float2 w2 = cis(-6.283185307179586f * (float)j2 / 256.0f);
    float2 w3 = cis(-6.283185307179586f * (float)j3 / 32.0f);
    float2 a1 = w1, a2 = w2, a3 = w3;
#pragma unroll
    for (int kk = 0; kk < 7; ++kk) {
      t1re[kk] = __float2half2_rn(a1.x); t1im[kk] = __float2half2_rn(a1.y);
      t2re[kk] = __float2half2_rn(a2.x); t2im[kk] = __float2half2_rn(a2.y);
      t3re[kk] = __float2half2_rn(a3.x); t3im[kk] = __float2half2_rn(a3.y);
      a1 = cmul(a1, w1); a2 = cmul(a2, w2); a3 = cmul(a3, w3);
    }
  }
  int base2 = (t >> 5) * 256 + j2;
  int base3 = (t >> 2) * 32 + j3;
  float2 acc[8];
#pragma unroll
  for (int kk = 0; kk < 8; ++kk) acc[kk] = make_float2(0.f, 0.f);
  __syncthreads();                        // staging visible

  for (int p = 0; p < 2; ++p) {
    uint2* R = dbuf + (size_t)p * RS_;
    hc v[8];
    // stage 1 (M=2048), in-place per thread
#pragma unroll
    for (int m = 0; m < 8; ++m) { uint2 u = R[sg(t + 256 * m)]; v[m].re = u2h(u.x); v[m].im = u2h(u.y); }
    hdft8<-1>(v);
#pragma unroll
    for (int kk = 1; kk < 8; ++kk) v[kk] = hcmul(v[kk], t1re[kk - 1], t1im[kk - 1]);
#pragma unroll
    for (int kk = 0; kk < 8; ++kk) R[sg(t + 256 * kk)] = make_uint2(h2u(v[kk].re), h2u(v[kk].im));
    __syncthreads();
    // stage 2 (M=256)
#pragma unroll
    for (int m = 0; m < 8; ++m) { uint2 u = R[sg(base2 + 32 * m)]; v[m].re = u2h(u.x); v[m].im = u2h(u.y); }
    hdft8<-1>(v);
#pragma unroll
    for (int kk = 1; kk < 8; ++kk) v[kk] = hcmul(v[kk], t2re[kk - 1], t2im[kk - 1]);
#pragma unroll
    for (int kk = 0; kk < 8; ++kk) R[sg(base2 + 32 * kk)] = make_uint2(h2u(v[kk].re), h2u(v[kk].im));
    __syncthreads();
    // stage 3 (M=32)
#pragma unroll
    for (int m = 0; m < 8; ++m) { uint2 u = R[sg(base3 + 4 * m)]; v[m].re = u2h(u.x); v[m].im = u2h(u.y); }
    hdft8<-1>(v);
#pragma unroll
    for (int kk = 1; kk < 8; ++kk) v[kk] = hcmul(v[kk], t3re[kk - 1], t3im[kk - 1]);
#pragma unroll
    for (int kk = 0; kk < 8; ++kk) R[sg(base3 + 4 * kk)] = make_uint2(h2u(v[kk].re), h2u(v[kk].im));
    __syncthreads();
    // stage 4 (M=4 radix-4, thread-private quads 8t..8t+7)
#pragma unroll
    for (int kk = 0; kk < 8; ++kk) { uint2 u = R[sg(8 * t + kk)]; v[kk].re = u2h(u.x); v[kk].im = u2h(u.y); }
    hdft4<-1>(v[0], v[1], v[2], v[3]); hdft4<-1>(v[4], v[5], v[6], v[7]);
#pragma unroll
    for (int kk = 0; kk < 8; ++kk) R[sg(8 * t + kk)] = make_uint2(h2u(v[kk].re), h2u(v[kk].im));
    __syncthreads();
    // product: P = Qf*conj(Kf), -f by digit arithmetic; fp32 accumulate both
    // channels of the pair. Next pass touches the OTHER region -> no trailing barrier.
#pragma unroll
    for (int kk = 0; kk < 8; ++kk) {
      int pos = 8 * t + kk;
      int f  = ((pos >> 8) & 7) | (((pos >> 5) & 7) << 3) | (((pos >> 2) & 7) << 6) | ((pos & 3) << 9);
      int fp = (2048 - f) & 2047;
      int pp = ((fp & 7) << 8) | (((fp >> 3) & 7) << 5) | (((fp >> 6) & 7) << 2) | ((fp >> 9) & 3);
      uint2 ub = R[sg(pp)];
      __half2 bre = u2h(ub.x), bim = u2h(ub.y);
      float ar0 = __low2float(v[kk].re),  ar1 = __high2float(v[kk].re);
      float ai0 = __low2float(v[kk].im),  ai1 = __high2float(v[kk].im);
      float br0 = __low2float(bre),       br1 = __high2float(bre);
      float bi0 = __low2float(bim),       bi1 = __high2float(bim);
      acc[kk].x += 0.5f  * ((br0 * ai0 + bi0 * ar0) + (br1 * ai1 + bi1 * ar1));
      acc[kk].y += 0.25f * ((ar0 * ar0 + ai0 * ai0 - br0 * br0 - bi0 * bi0)
                          + (ar1 * ar1 + ai1 * ai1 - br1 * br1 - bi1 * bi1));
    }
  }
  // park fp32 sums into region 0 (dead: its last read, pass-0 product, is 4+
  // barriers behind), then coalesced 256-wide store.
  {
    float2* pk0 = (float2*)dbuf;
#pragma unroll
    for (int kk = 0; kk < 8; ++kk) pk0[sg(8 * t + kk)] = acc[kk];
  }
  __syncthreads();
  {
    const float2* pk0 = (const float2*)dbuf;
    float2* prow = part + (size_t)l * L_;
#pragma unroll
    for (int m = 0; m < 8; ++m) {
      int p = t + 256 * m;
      prow[p] = pk0[sg(p)];
    }
  }
}

// ---------- kernel R: sum 128 partial rows -> S[b][p] ----------
__global__ __launch_bounds__(256) void reduce_S_kernel(
    const float2* __restrict__ part, float2* __restrict__ S) {
  int idx = blockIdx.x * 256 + threadIdx.x;   // 0..32767 = [b][p]
  int p = idx & 2047;
  int b = idx >> 11;
  float2 s = make_float2(0.f, 0.f);
#pragma unroll 4
  for (int i = 0; i < 128; ++i) {
    float2 vv = part[(size_t)(b * 128 + i) * L_ + p];
    s.x += vv.x; s.y += vv.y;
  }
  S[idx] = s;
}

// ---------- kernel I: mirrored DIT inverse (digit-reversed in, natural out) ----------
__global__ __launch_bounds__(256) void ifft_kernel(
    const float2* __restrict__ S, float* __restrict__ mv) {
  __shared__ float2 buf[2176];
  int t = threadIdx.x, b = blockIdx.x;
  int j2 = t & 31, j3 = t & 3;
  float2 tw1[7], tw2[7], tw3[7];
  {
    float2 w1 = cis(6.283185307179586f * (float)t  / 2048.0f);
    float2 w2 = cis(6.283185307179586f * (float)j2 / 256.0f);
    float2 w3 = cis(6.283185307179586f * (float)j3 / 32.0f);
    tw1[0] = w1; tw2[0] = w2; tw3[0] = w3;
#pragma unroll
    for (int kk = 1; kk < 7; ++kk) {
      tw1[kk] = cmul(tw1[kk - 1], w1);
      tw2[kk] = cmul(tw2[kk - 1], w2);
      tw3[kk] = cmul(tw3[kk - 1], w3);
    }
  }
  int base2 = (t >> 5) * 256 + j2;
  int base3 = (t >> 2) * 32 + j3;
  // stage A: M=4 DFT (no twiddle), quads 8t..8t+7
  float2 u[8];
  {
    const float4* rp = (const float4*)(S + (size_t)b * L_);
#pragma unroll
    for (int m = 0; m < 4; ++m) {
      float4 f = rp[4 * t + m];
      u[2 * m]     = make_float2(f.x, f.y);
      u[2 * m + 1] = make_float2(f.z, f.w);
    }
  }
  dft4<1>(u[0], u[1], u[2], u[3]);
  dft4<1>(u[4], u[5], u[6], u[7]);
#pragma unroll
  for (int kk = 0; kk < 8; ++kk) buf[sg(8 * t + kk)] = u[kk];
  __syncthreads();
  // stage B: M=32
  float2 v[8];
#pragma unroll
  for (int kk = 0; kk < 8; ++kk) v[kk] = buf[sg(base3 + 4 * kk)];
#pragma unroll
  for (int kk = 1; kk < 8; ++kk) v[kk] = cmul(v[kk], tw3[kk - 1]);
  dft8<1>(v);
  __syncthreads();
#pragma unroll
  for (int m = 0; m < 8; ++m) buf[sg(base3 + 4 * m)] = v[m];
  __syncthreads();
  // stage C: M=256
#pragma unroll
  for (int kk = 0; kk < 8; ++kk) v[kk] = buf[sg(base2 + 32 * kk)];
#pragma unroll
  for (int kk = 1; kk < 8; ++kk) v[kk] = cmul(v[kk], tw2[kk - 1]);
  dft8<1>(v);
  __syncthreads();
#pragma unroll
  for (int m = 0; m < 8; ++m) buf[sg(base2 + 32 * m)] = v[m];
  __syncthreads();
  // stage D: M=2048 -> natural order
#pragma unroll
  for (int kk = 0; kk < 8; ++kk) v[kk] = buf[sg(t + 256 * kk)];
#pragma unroll
  for (int kk = 1; kk < 8; ++kk) v[kk] = cmul(v[kk], tw1[kk - 1]);
  dft8<1>(v);
  const float scale = 1.0f / (2048.0f * 512.0f);  // 1/N * mean over H*E
#pragma unroll
  for (int m = 0; m < 8; ++m) mv[b * L_ + t + 256 * m] = v[m].x * scale;
}

// ---------- kernel K: batch-mean top-7 + per-batch softmax weights ----------
__global__ __launch_bounds__(256) void topk_kernel(
    const float* __restrict__ mv, int* __restrict__ topk, float* __restrict__ wts) {
  __shared__ float av[2048];
  __shared__ float rv[256];
  __shared__ int   ri[256];
  __shared__ int   sidx[K_];
  int tid = threadIdx.x;
  for (int d = tid; d < 2048; d += 256) {
    float s = 0.f;
#pragma unroll
    for (int b = 0; b < B_; ++b) s += mv[b * L_ + d];
    av[d] = s;
  }
  __syncthreads();
  for (int kk = 0; kk < K_; ++kk) {
    float bv = -INFINITY; int bi = 0;
    for (int d = tid; d < 2048; d += 256) {
      float vv = av[d];
      if (vv > bv) { bv = vv; bi = d; }
    }
    rv[tid] = bv; ri[tid] = bi;
    __syncthreads();
    for (int off = 128; off > 0; off >>= 1) {
      if (tid < off) {
        float v2 = rv[tid + off]; int i2 = ri[tid + off];
        if (v2 > rv[tid] || (v2 == rv[tid] && i2 < ri[tid])) { rv[tid] = v2; ri[tid] = i2; }
      }
      __syncthreads();
    }
    if (tid == 0) { sidx[kk] = ri[0]; av[ri[0]] = -INFINITY; }
    __syncthreads();
  }
  if (tid < K_) topk[tid] = sidx[tid];
  if (tid < B_) {
    float xk[K_], m = -INFINITY;
#pragma unroll
    for (int kk = 0; kk < K_; ++kk) { xk[kk] = mv[tid * L_ + sidx[kk]]; m = fmaxf(m, xk[kk]); }
    float s = 0.f;
#pragma unroll
    for (int kk = 0; kk < K_; ++kk) { xk[kk] = expf(xk[kk] - m); s += xk[kk]; }
#pragma unroll
    for (int kk = 0; kk < K_; ++kk) wts[tid * K_ + kk] = xk[kk] / s;
  }
}

// ---------- kernel G: out[b,t,h,e] = sum_k w[b,k] * v[b,(t+d_k)%L,h,e] ----------
__global__ __launch_bounds__(256) void aggregate_kernel(
    const float4* __restrict__ v4, const int* __restrict__ topk,
    const float* __restrict__ wts, float4* __restrict__ out4) {
  __shared__ int   sidx[K_];
  __shared__ float sw[B_][K_];
  int tid = threadIdx.x;
  if (tid < K_) sidx[tid] = topk[tid];
  if (tid < B_ * K_) sw[tid / K_][tid % K_] = wts[tid];
  __syncthreads();
  int idx = blockIdx.x * 256 + tid;
  int c4  = idx & 127;
  int row = idx >> 7;
  int t   = row & (L_ - 1);
  int b   = row >> 11;
  float4 acc = make_float4(0.f, 0.f, 0.f, 0.f);
#pragma unroll
  for (int kk = 0; kk < K_; ++kk) {
    int s = t + sidx[kk];
    if (s >= L_) s -= L_;
    float w = sw[b][kk];
    float4 val = v4[((size_t)(b * L_ + s) << 7) + c4];
    acc.x += w * val.x; acc.y += w * val.y;
    acc.z += w * val.z; acc.w += w * val.w;
  }
  out4[idx] = acc;
}

extern "C" void kernel_launch(void* const* d_in, const int* in_sizes, int n_in,
                              void* d_out, int out_size, void* d_ws, size_t ws_size,
                              hipStream_t stream) {
  const float* q = (const float*)d_in[0];
  const float* k = (const float*)d_in[1];
  const float* v = (const float*)d_in[2];
  float* out = (float*)d_out;

  char* ws = (char*)d_ws;
  float4* z    = (float4*)(ws + Z_OFF);
  float2* part = (float2*)(ws + PART_OFF);
  float2* S    = (float2*)(ws + S_OFF);
  float*  mv   = (float*) (ws + MV_OFF);
  int*    topk = (int*)   (ws + TK_OFF);
  float*  wts  = (float*) (ws + W_OFF);

  pack_kernel<<<B_ * 64, 512, 4224 * sizeof(float4), stream>>>(q, k, z);
  fft_corr_kernel<<<B_ * 128, 256, 2 * RS_ * sizeof(uint2), stream>>>(z, part);
  reduce_S_kernel<<<(B_ * L_) / 256, 256, 0, stream>>>(part, S);
  ifft_kernel<<<B_, 256, 0, stream>>>(S, mv);
  topk_kernel<<<1, 256, 0, stream>>>(mv, topk, wts);
  aggregate_kernel<<<(B_ * L_ * H_ * E_ / 4) / 256, 256, 0, stream>>>(
      (const float4*)v, topk, wts, (float4*)out);
}

// Round 12
// 156.250 us; speedup vs baseline: 1.1715x; 1.0229x over previous
//
#include <hip/hip_runtime.h>
#include <hip/hip_bf16.h>
#include <hip/hip_fp16.h>
#include <math.h>

// AutoCorrelation (Autoformer). B=16, L=2048, H=8, E=64, fp32.
// Round 12: (a) fft processes BOTH pair-regions in one pass (dual register
// sets v0/v1 -> 2 independent dep chains per stage, barriers 9->6);
// (b) pack preloads all 16 float4s before LDS stores (16 loads in flight).
// Everything else byte-identical to validated r11.

#define B_ 16
#define L_ 2048
#define H_ 8
#define E_ 64
#define K_ 7
#define RS_ 2178          // region stride in uint2 (8B) units; sg(2047)=2174 < RS_

// ---------- workspace layout ----------
#define Z_OFF    0ull                              // fp16 slabs: 1024 x 64KB = 64 MiB
#define PART_OFF 67108864ull                       // float2[2048][2048] = 32 MiB
#define S_OFF    (PART_OFF + 33554432ull)          // float2[16][2048] = 256 KiB
#define MV_OFF   (S_OFF + 262144ull)               // float [B][L]
#define TK_OFF   (MV_OFF + 131072ull)              // int[7]
#define W_OFF    (TK_OFF + 64ull)                  // float[16][7]

// ---------- fp32 complex helpers (ifft/twiddle gen) ----------
__device__ __forceinline__ float2 cadd(float2 a, float2 b) { return make_float2(a.x + b.x, a.y + b.y); }
__device__ __forceinline__ float2 csub(float2 a, float2 b) { return make_float2(a.x - b.x, a.y - b.y); }
__device__ __forceinline__ float2 cmul(float2 a, float2 b) {
  return make_float2(fmaf(a.x, b.x, -a.y * b.y), fmaf(a.x, b.y, a.y * b.x));
}
__device__ __forceinline__ float2 cis(float ang) { float s, c; sincosf(ang, &s, &c); return make_float2(c, s); }

template<int S> __device__ __forceinline__ float2 rot90(float2 z) {
  return (S < 0) ? make_float2(z.y, -z.x) : make_float2(-z.y, z.x);
}
template<int S> __device__ __forceinline__ void dft4(float2& a, float2& b, float2& c, float2& d) {
  float2 t0 = cadd(a, c), t1 = csub(a, c), t2 = cadd(b, d), t3 = rot90<S>(csub(b, d));
  a = cadd(t0, t2); c = csub(t0, t2); b = cadd(t1, t3); d = csub(t1, t3);
}
template<int S> __device__ __forceinline__ void dft8(float2 v[8]) {
  const float RT = 0.70710678118654752f;
  const float SR = (S < 0) ? -RT : RT;
  float2 a0 = cadd(v[0], v[4]), a1 = cadd(v[1], v[5]), a2 = cadd(v[2], v[6]), a3 = cadd(v[3], v[7]);
  float2 b0 = csub(v[0], v[4]), b1 = csub(v[1], v[5]), b2 = csub(v[2], v[6]), b3 = csub(v[3], v[7]);
  b1 = cmul(b1, make_float2(RT, SR));
  b2 = rot90<S>(b2);
  b3 = cmul(b3, make_float2(-RT, SR));
  dft4<S>(a0, a1, a2, a3);
  dft4<S>(b0, b1, b2, b3);
  v[0] = a0; v[2] = a1; v[4] = a2; v[6] = a3;
  v[1] = b0; v[3] = b1; v[5] = b2; v[7] = b3;
}
// padded index: +1 element per 16 (<=2-way across all stage patterns)
__device__ __forceinline__ int sg(int e) { return e + (e >> 4); }

// ---------- packed-fp16 complex (channel pair per __half2 lane-slot) ----------
struct hc { __half2 re, im; };
__device__ __forceinline__ hc hcadd(hc a, hc b) { return { __hadd2(a.re, b.re), __hadd2(a.im, b.im) }; }
__device__ __forceinline__ hc hcsub(hc a, hc b) { return { __hsub2(a.re, b.re), __hsub2(a.im, b.im) }; }
template<int S> __device__ __forceinline__ hc hrot90(hc z) {       // *(-i) fwd
  hc r; if (S < 0) { r.re = z.im; r.im = __hneg2(z.re); } else { r.re = __hneg2(z.im); r.im = z.re; }
  return r;
}
__device__ __forceinline__ hc hcmul(hc v, __half2 wre, __half2 wim) {
  hc r;
  r.re = __hsub2(__hmul2(v.re, wre), __hmul2(v.im, wim));
  r.im = __hfma2(v.re, wim, __hmul2(v.im, wre));
  return r;
}
template<int S> __device__ __forceinline__ void hdft4(hc& a, hc& b, hc& c, hc& d) {
  hc t0 = hcadd(a, c), t1 = hcsub(a, c), t2 = hcadd(b, d), t3 = hrot90<S>(hcsub(b, d));
  a = hcadd(t0, t2); c = hcsub(t0, t2); b = hcadd(t1, t3); d = hcsub(t1, t3);
}
template<int S> __device__ __forceinline__ void hdft8(hc v[8]) {
  const float RT = 0.70710678118654752f;
  __half2 rt  = __float2half2_rn(RT);
  __half2 sr  = __float2half2_rn((S < 0) ? -RT : RT);
  __half2 nrt = __float2half2_rn(-RT);
  hc a0 = hcadd(v[0], v[4]), a1 = hcadd(v[1], v[5]), a2 = hcadd(v[2], v[6]), a3 = hcadd(v[3], v[7]);
  hc b0 = hcsub(v[0], v[4]), b1 = hcsub(v[1], v[5]), b2 = hcsub(v[2], v[6]), b3 = hcsub(v[3], v[7]);
  b1 = hcmul(b1, rt, sr);
  b2 = hrot90<S>(b2);
  b3 = hcmul(b3, nrt, sr);
  hdft4<S>(a0, a1, a2, a3);
  hdft4<S>(b0, b1, b2, b3);
  v[0] = a0; v[2] = a1; v[4] = a2; v[6] = a3;
  v[1] = b0; v[3] = b1; v[5] = b2; v[7] = b3;
}
__device__ __forceinline__ __half2 u2h(unsigned u) { return __builtin_bit_cast(__half2, u); }
__device__ __forceinline__ unsigned h2u(__half2 h) { return __builtin_bit_cast(unsigned, h); }

// ---------- kernel P: row-sequential pack q,k -> pair-packed fp16 slabs ----------
// Block (b,tile): reads 32 full 2KB rows of q,k (contiguous); writes one 64KB
// contiguous slab. All 16 float4 loads issued BEFORE any LDS store (16 in
// flight; r11 serialized load->store 8x). f4 at (cq,j) = [re01,im01,re23,im23].
__global__ __launch_bounds__(512) void pack_kernel(
    const float* __restrict__ q, const float* __restrict__ k,
    float4* __restrict__ z) {
  extern __shared__ float4 tile[];        // [128][33] = 4224 f4 = 67584 B
  int tid = threadIdx.x;
  int l = blockIdx.x;                     // b*64 + tileIdx
  int tl = l & 63, b = l >> 6;
  size_t rowbase = ((size_t)b * L_ + tl * 32) * 512;
  const float4* q4 = (const float4*)(q + rowbase);
  const float4* k4 = (const float4*)(k + rowbase);
  int cq = tid & 127;
  int j0 = tid >> 7;                      // 0..3
  float4 qv[8], kv[8];
#pragma unroll
  for (int pass = 0; pass < 8; ++pass) {
    int j = pass * 4 + j0;
    qv[pass] = q4[j * 128 + cq];
    kv[pass] = k4[j * 128 + cq];
  }
#pragma unroll
  for (int pass = 0; pass < 8; ++pass) {
    int j = pass * 4 + j0;
    float4 pk;
    ((__half2*)&pk)[0] = __float22half2_rn(make_float2(qv[pass].x, qv[pass].y));  // re01
    ((__half2*)&pk)[1] = __float22half2_rn(make_float2(kv[pass].x, kv[pass].y));  // im01
    ((__half2*)&pk)[2] = __float22half2_rn(make_float2(qv[pass].z, qv[pass].w));  // re23
    ((__half2*)&pk)[3] = __float22half2_rn(make_float2(kv[pass].z, kv[pass].w));  // im23
    tile[cq * 33 + j] = pk;
  }
  __syncthreads();
  float4* slab = z + (size_t)l * 4096;
#pragma unroll
  for (int pass = 0; pass < 8; ++pass) {
    int m = pass * 512 + tid;
    int c = m >> 5, j = m & 31;
    slab[c * 32 + j] = tile[c * 33 + j];
  }
}

// ---------- kernel F: packed-fp16 radix-8/8/8/4 DIF FFT + freq product ----------
// Block (b, cg): channels 4cg..4cg+3 as 2 packed pairs processed TOGETHER
// (dual register sets, one barrier per stage). 256 threads; 2 LDS regions of
// RS_ uint2. Digit-reversed storage pos=256k1+32k2+4k3+k4, f=k1+8k2+64k3+512k4.
__global__ __launch_bounds__(256, 4) void fft_corr_kernel(
    const float4* __restrict__ z, float2* __restrict__ part) {
  extern __shared__ uint2 dbuf[];         // 2 regions x RS_ uint2 = 34848 B
  int t = threadIdx.x;
  int j2 = t & 31, j3 = t & 3;
  int l = blockIdx.x;                     // b*128 + cg
  int cg = l & 127, b = l >> 7;
  const float4* zb = z + (size_t)b * 64 * 4096;

  // ---- staging: 64 tiles x 32 j of cq=cg -> 512B contiguous runs
#pragma unroll
  for (int it = 0; it < 8; ++it) {
    int m = it * 256 + t;
    int tl = m >> 5, j = m & 31;
    float4 pk = zb[(size_t)tl * 4096 + cg * 32 + j];
    int sp = sg(tl * 32 + j);
    dbuf[sp]       = make_uint2(__float_as_uint(pk.x), __float_as_uint(pk.y));
    dbuf[RS_ + sp] = make_uint2(__float_as_uint(pk.z), __float_as_uint(pk.w));
  }

  // twiddles: fp32 iterative chains -> broadcast half2
  __half2 t1re[7], t1im[7], t2re[7], t2im[7], t3re[7], t3im[7];
  {
    float2 w1 = cis(-6.283185307179586f * (float)t  / 2048.0f);
    float2 w2 = cis(-6.283185307179586f * (float)j2 / 256.0f);
    float2 w3 = cis(-6.283185307179586f * (float)j3 / 32.0f);
    float2 a1 = w1, a2 = w2, a3 = w3;
#pragma unroll
    for (int kk = 0; kk < 7; ++kk) {
      t1re[kk] = __float2half2_rn(a1.x); t1im[kk] = __float2half2_rn(a1.y);
      t2re[kk] = __float2half2_rn(a2.x); t2im[kk] = __float2half2_rn(a2.y);
      t3re[kk] = __float2half2_rn(a3.x); t3im[kk] = __float2half2_rn(a3.y);
      a1 = cmul(a1, w1); a2 = cmul(a2, w2); a3 = cmul(a3, w3);
    }
  }
  int base2 = (t >> 5) * 256 + j2;
  int base3 = (t >> 2) * 32 + j3;
  uint2* R0 = dbuf;
  uint2* R1 = dbuf + RS_;
  hc v0[8], v1[8];
  __syncthreads();                        // staging visible

  // ---- stage 1 (M=2048), both regions, in-place per thread
#pragma unroll
  for (int m = 0; m < 8; ++m) {
    uint2 u = R0[sg(t + 256 * m)]; v0[m].re = u2h(u.x); v0[m].im = u2h(u.y);
    u = R1[sg(t + 256 * m)];       v1[m].re = u2h(u.x); v1[m].im = u2h(u.y);
  }
  hdft8<-1>(v0); hdft8<-1>(v1);
#pragma unroll
  for (int kk = 1; kk < 8; ++kk) {
    v0[kk] = hcmul(v0[kk], t1re[kk - 1], t1im[kk - 1]);
    v1[kk] = hcmul(v1[kk], t1re[kk - 1], t1im[kk - 1]);
  }
#pragma unroll
  for (int kk = 0; kk < 8; ++kk) {
    R0[sg(t + 256 * kk)] = make_uint2(h2u(v0[kk].re), h2u(v0[kk].im));
    R1[sg(t + 256 * kk)] = make_uint2(h2u(v1[kk].re), h2u(v1[kk].im));
  }
  __syncthreads();
  // ---- stage 2 (M=256)
#pragma unroll
  for (int m = 0; m < 8; ++m) {
    uint2 u = R0[sg(base2 + 32 * m)]; v0[m].re = u2h(u.x); v0[m].im = u2h(u.y);
    u = R1[sg(base2 + 32 * m)];       v1[m].re = u2h(u.x); v1[m].im = u2h(u.y);
  }
  hdft8<-1>(v0); hdft8<-1>(v1);
#pragma unroll
  for (int kk = 1; kk < 8; ++kk) {
    v0[kk] = hcmul(v0[kk], t2re[kk - 1], t2im[kk - 1]);
    v1[kk] = hcmul(v1[kk], t2re[kk - 1], t2im[kk - 1]);
  }
#pragma unroll
  for (int kk = 0; kk < 8; ++kk) {
    R0[sg(base2 + 32 * kk)] = make_uint2(h2u(v0[kk].re), h2u(v0[kk].im));
    R1[sg(base2 + 32 * kk)] = make_uint2(h2u(v1[kk].re), h2u(v1[kk].im));
  }
  __syncthreads();
  // ---- stage 3 (M=32)
#pragma unroll
  for (int m = 0; m < 8; ++m) {
    uint2 u = R0[sg(base3 + 4 * m)]; v0[m].re = u2h(u.x); v0[m].im = u2h(u.y);
    u = R1[sg(base3 + 4 * m)];       v1[m].re = u2h(u.x); v1[m].im = u2h(u.y);
  }
  hdft8<-1>(v0); hdft8<-1>(v1);
#pragma unroll
  for (int kk = 1; kk < 8; ++kk) {
    v0[kk] = hcmul(v0[kk], t3re[kk - 1], t3im[kk - 1]);
    v1[kk] = hcmul(v1[kk], t3re[kk - 1], t3im[kk - 1]);
  }
#pragma unroll
  for (int kk = 0; kk < 8; ++kk) {
    R0[sg(base3 + 4 * kk)] = make_uint2(h2u(v0[kk].re), h2u(v0[kk].im));
    R1[sg(base3 + 4 * kk)] = make_uint2(h2u(v1[kk].re), h2u(v1[kk].im));
  }
  __syncthreads();
  // ---- stage 4 (M=4 radix-4, thread-private quads 8t..8t+7)
#pragma unroll
  for (int kk = 0; kk < 8; ++kk) {
    uint2 u = R0[sg(8 * t + kk)]; v0[kk].re = u2h(u.x); v0[kk].im = u2h(u.y);
    u = R1[sg(8 * t + kk)];       v1[kk].re = u2h(u.x); v1[kk].im = u2h(u.y);
  }
  hdft4<-1>(v0[0], v0[1], v0[2], v0[3]); hdft4<-1>(v0[4], v0[5], v0[6], v0[7]);
  hdft4<-1>(v1[0], v1[1], v1[2], v1[3]); hdft4<-1>(v1[4], v1[5], v1[6], v1[7]);
#pragma unroll
  for (int kk = 0; kk < 8; ++kk) {
    R0[sg(8 * t + kk)] = make_uint2(h2u(v0[kk].re), h2u(v0[kk].im));
    R1[sg(8 * t + kk)] = make_uint2(h2u(v1[kk].re), h2u(v1[kk].im));
  }
  __syncthreads();
  // ---- product: P = Qf*conj(Kf), -f by digit arithmetic; fp32 accumulate
  // all 4 channels (2 per region).
  float2 acc[8];
#pragma unroll
  for (int kk = 0; kk < 8; ++kk) {
    int pos = 8 * t + kk;
    int f  = ((pos >> 8) & 7) | (((pos >> 5) & 7) << 3) | (((pos >> 2) & 7) << 6) | ((pos & 3) << 9);
    int fp = (2048 - f) & 2047;
    int pp = ((fp & 7) << 8) | (((fp >> 3) & 7) << 5) | (((fp >> 6) & 7) << 2) | ((fp >> 9) & 3);
    float sx = 0.f, sy = 0.f;
    {
      uint2 ub = R0[sg(pp)];
      __half2 bre = u2h(ub.x), bim = u2h(ub.y);
      float ar0 = __low2float(v0[kk].re),  ar1 = __high2float(v0[kk].re);
      float ai0 = __low2float(v0[kk].im),  ai1 = __high2float(v0[kk].im);
      float br0 = __low2float(bre),        br1 = __high2float(bre);
      float bi0 = __low2float(bim),        bi1 = __high2float(bim);
      sx += (br0 * ai0 + bi0 * ar0) + (br1 * ai1 + bi1 * ar1);
      sy += (ar0 * ar0 + ai0 * ai0 - br0 * br0 - bi0 * bi0)
          + (ar1 * ar1 + ai1 * ai1 - br1 * br1 - bi1 * bi1);
    }
    {
      uint2 ub = R1[sg(pp)];
      __half2 bre = u2h(ub.x), bim = u2h(ub.y);
      float ar0 = __low2float(v1[kk].re),  ar1 = __high2float(v1[kk].re);
      float ai0 = __low2float(v1[kk].im),  ai1 = __high2float(v1[kk].im);
      float br0 = __low2float(bre),        br1 = __high2float(bre);
      float bi0 = __low2float(bim),        bi1 = __high2float(bim);
      sx += (br0 * ai0 + bi0 * ar0) + (br1 * ai1 + bi1 * ar1);
      sy += (ar0 * ar0 + ai0 * ai0 - br0 * br0 - bi0 * bi0)
          + (ar1 * ar1 + ai1 * ai1 - br1 * br1 - bi1 * bi1);
    }
    acc[kk] = make_float2(0.5f * sx, 0.25f * sy);
  }
  __syncthreads();                        // product reads of R0/R1 complete
  // park fp32 sums into region 0, then coalesced 256-wide store.
  {
    float2* pk0 = (float2*)dbuf;
#pragma unroll
    for (int kk = 0; kk < 8; ++kk) pk0[sg(8 * t + kk)] = acc[kk];
  }
  __syncthreads();
  {
    const float2* pk0 = (const float2*)dbuf;
    float2* prow = part + (size_t)l * L_;
#pragma unroll
    for (int m = 0; m < 8; ++m) {
      int p = t + 256 * m;
      prow[p] = pk0[sg(p)];
    }
  }
}

// ---------- kernel R: sum 128 partial rows -> S[b][p] ----------
__global__ __launch_bounds__(256) void reduce_S_kernel(
    const float2* __restrict__ part, float2* __restrict__ S) {
  int idx = blockIdx.x * 256 + threadIdx.x;   // 0..32767 = [b][p]
  int p = idx & 2047;
  int b = idx >> 11;
  float2 s = make_float2(0.f, 0.f);
#pragma unroll 4
  for (int i = 0; i < 128; ++i) {
    float2 vv = part[(size_t)(b * 128 + i) * L_ + p];
    s.x += vv.x; s.y += vv.y;
  }
  S[idx] = s;
}

// ---------- kernel I: mirrored DIT inverse (digit-reversed in, natural out) ----------
__global__ __launch_bounds__(256) void ifft_kernel(
    const float2* __restrict__ S, float* __restrict__ mv) {
  __shared__ float2 buf[2176];
  int t = threadIdx.x, b = blockIdx.x;
  int j2 = t & 31, j3 = t & 3;
  float2 tw1[7], tw2[7], tw3[7];
  {
    float2 w1 = cis(6.283185307179586f * (float)t  / 2048.0f);
    float2 w2 = cis(6.283185307179586f * (float)j2 / 256.0f);
    float2 w3 = cis(6.283185307179586f * (float)j3 / 32.0f);
    tw1[0] = w1; tw2[0] = w2; tw3[0] = w3;
#pragma unroll
    for (int kk = 1; kk < 7; ++kk) {
      tw1[kk] = cmul(tw1[kk - 1], w1);
      tw2[kk] = cmul(tw2[kk - 1], w2);
      tw3[kk] = cmul(tw3[kk - 1], w3);
    }
  }
  int base2 = (t >> 5) * 256 + j2;
  int base3 = (t >> 2) * 32 + j3;
  // stage A: M=4 DFT (no twiddle), quads 8t..8t+7
  float2 u[8];
  {
    const float4* rp = (const float4*)(S + (size_t)b * L_);
#pragma unroll
    for (int m = 0; m < 4; ++m) {
      float4 f = rp[4 * t + m];
      u[2 * m]     = make_float2(f.x, f.y);
      u[2 * m + 1] = make_float2(f.z, f.w);
    }
  }
  dft4<1>(u[0], u[1], u[2], u[3]);
  dft4<1>(u[4], u[5], u[6], u[7]);
#pragma unroll
  for (int kk = 0; kk < 8; ++kk) buf[sg(8 * t + kk)] = u[kk];
  __syncthreads();
  // stage B: M=32
  float2 v[8];
#pragma unroll
  for (int kk = 0; kk < 8; ++kk) v[kk] = buf[sg(base3 + 4 * kk)];
#pragma unroll
  for (int kk = 1; kk < 8; ++kk) v[kk] = cmul(v[kk], tw3[kk - 1]);
  dft8<1>(v);
  __syncthreads();
#pragma unroll
  for (int m = 0; m < 8; ++m) buf[sg(base3 + 4 * m)] = v[m];
  __syncthreads();
  // stage C: M=256
#pragma unroll
  for (int kk = 0; kk < 8; ++kk) v[kk] = buf[sg(base2 + 32 * kk)];
#pragma unroll
  for (int kk = 1; kk < 8; ++kk) v[kk] = cmul(v[kk], tw2[kk - 1]);
  dft8<1>(v);
  __syncthreads();
#pragma unroll
  for (int m = 0; m < 8; ++m) buf[sg(base2 + 32 * m)] = v[m];
  __syncthreads();
  // stage D: M=2048 -> natural order
#pragma unroll
  for (int kk = 0; kk < 8; ++kk) v[kk] = buf[sg(t + 256 * kk)];
#pragma unroll
  for (int kk = 1; kk < 8; ++kk) v[kk] = cmul(v[kk], tw1[kk - 1]);
  dft8<1>(v);
  const float scale = 1.0f / (2048.0f * 512.0f);  // 1/N * mean over H*E
#pragma unroll
  for (int m = 0; m < 8; ++m) mv[b * L_ + t + 256 * m] = v[m].x * scale;
}

// ---------- kernel K: batch-mean top-7 + per-batch softmax weights ----------
__global__ __launch_bounds__(256) void topk_kernel(
    const float* __restrict__ mv, int* __restrict__ topk, float* __restrict__ wts) {
  __shared__ float av[2048];
  __shared__ float rv[256];
  __shared__ int   ri[256];
  __shared__ int   sidx[K_];
  int tid = threadIdx.x;
  for (int d = tid; d < 2048; d += 256) {
    float s = 0.f;
#pragma unroll
    for (int b = 0; b < B_; ++b) s += mv[b * L_ + d];
    av[d] = s;
  }
  __syncthreads();
  for (int kk = 0; kk < K_; ++kk) {
    float bv = -INFINITY; int bi = 0;
    for (int d = tid; d < 2048; d += 256) {
      float vv = av[d];
      if (vv > bv) { bv = vv; bi = d; }
    }
    rv[tid] = bv; ri[tid] = bi;
    __syncthreads();
    for (int off = 128; off > 0; off >>= 1) {
      if (tid < off) {
        float v2 = rv[tid + off]; int i2 = ri[tid + off];
        if (v2 > rv[tid] || (v2 == rv[tid] && i2 < ri[tid])) { rv[tid] = v2; ri[tid] = i2; }
      }
      __syncthreads();
    }
    if (tid == 0) { sidx[kk] = ri[0]; av[ri[0]] = -INFINITY; }
    __syncthreads();
  }
  if (tid < K_) topk[tid] = sidx[tid];
  if (tid < B_) {
    float xk[K_], m = -INFINITY;
#pragma unroll
    for (int kk = 0; kk < K_; ++kk) { xk[kk] = mv[tid * L_ + sidx[kk]]; m = fmaxf(m, xk[kk]); }
    float s = 0.f;
#pragma unroll
    for (int kk = 0; kk < K_; ++kk) { xk[kk] = expf(xk[kk] - m); s += xk[kk]; }
#pragma unroll
    for (int kk = 0; kk < K_; ++kk) wts[tid * K_ + kk] = xk[kk] / s;
  }
}

// ---------- kernel G: out[b,t,h,e] = sum_k w[b,k] * v[b,(t+d_k)%L,h,e] ----------
__global__ __launch_bounds__(256) void aggregate_kernel(
    const float4* __restrict__ v4, const int* __restrict__ topk,
    const float* __restrict__ wts, float4* __restrict__ out4) {
  __shared__ int   sidx[K_];
  __shared__ float sw[B_][K_];
  int tid = threadIdx.x;
  if (tid < K_) sidx[tid] = topk[tid];
  if (tid < B_ * K_) sw[tid / K_][tid % K_] = wts[tid];
  __syncthreads();
  int idx = blockIdx.x * 256 + tid;
  int c4  = idx & 127;
  int row = idx >> 7;
  int t   = row & (L_ - 1);
  int b   = row >> 11;
  float4 acc = make_float4(0.f, 0.f, 0.f, 0.f);
#pragma unroll
  for (int kk = 0; kk < K_; ++kk) {
    int s = t + sidx[kk];
    if (s >= L_) s -= L_;
    float w = sw[b][kk];
    float4 val = v4[((size_t)(b * L_ + s) << 7) + c4];
    acc.x += w * val.x; acc.y += w * val.y;
    acc.z += w * val.z; acc.w += w * val.w;
  }
  out4[idx] = acc;
}

extern "C" void kernel_launch(void* const* d_in, const int* in_sizes, int n_in,
                              void* d_out, int out_size, void* d_ws, size_t ws_size,
                              hipStream_t stream) {
  const float* q = (const float*)d_in[0];
  const float* k = (const float*)d_in[1];
  const float* v = (const float*)d_in[2];
  float* out = (float*)d_out;

  char* ws = (char*)d_ws;
  float4* z    = (float4*)(ws + Z_OFF);
  float2* part = (float2*)(ws + PART_OFF);
  float2* S    = (float2*)(ws + S_OFF);
  float*  mv   = (float*) (ws + MV_OFF);
  int*    topk = (int*)   (ws + TK_OFF);
  float*  wts  = (float*) (ws + W_OFF);

  pack_kernel<<<B_ * 64, 512, 4224 * sizeof(float4), stream>>>(q, k, z);
  fft_corr_kernel<<<B_ * 128, 256, 2 * RS_ * sizeof(uint2), stream>>>(z, part);
  reduce_S_kernel<<<(B_ * L_) / 256, 256, 0, stream>>>(part, S);
  ifft_kernel<<<B_, 256, 0, stream>>>(S, mv);
  topk_kernel<<<1, 256, 0, stream>>>(mv, topk, wts);
  aggregate_kernel<<<(B_ * L_ * H_ * E_ / 4) / 256, 256, 0, stream>>>(
      (const float4*)v, topk, wts, (float4*)out);
}

// Round 13
// 155.166 us; speedup vs baseline: 1.1797x; 1.0070x over previous
//
#include <hip/hip_runtime.h>
#include <hip/hip_bf16.h>
#include <hip/hip_fp16.h>
#include <math.h>

// AutoCorrelation (Autoformer). B=16, L=2048, H=8, E=64, fp32.
// Round 13: pack split into j-halves -> 2048 blocks, 34.8KB LDS, 4 blocks/CU
// (was 1024 blocks / 67.6KB / 2 per CU, pure-stall at 62us). Slab layout
// byte-identical (each half writes its disjoint 256B j-range per cq).
// fft/reduce/ifft/topk/aggregate byte-identical to validated r12.

#define B_ 16
#define L_ 2048
#define H_ 8
#define E_ 64
#define K_ 7
#define RS_ 2178          // region stride in uint2 (8B) units; sg(2047)=2174 < RS_

// ---------- workspace layout ----------
#define Z_OFF    0ull                              // fp16 slabs: 1024 x 64KB = 64 MiB
#define PART_OFF 67108864ull                       // float2[2048][2048] = 32 MiB
#define S_OFF    (PART_OFF + 33554432ull)          // float2[16][2048] = 256 KiB
#define MV_OFF   (S_OFF + 262144ull)               // float [B][L]
#define TK_OFF   (MV_OFF + 131072ull)              // int[7]
#define W_OFF    (TK_OFF + 64ull)                  // float[16][7]

// ---------- fp32 complex helpers (ifft/twiddle gen) ----------
__device__ __forceinline__ float2 cadd(float2 a, float2 b) { return make_float2(a.x + b.x, a.y + b.y); }
__device__ __forceinline__ float2 csub(float2 a, float2 b) { return make_float2(a.x - b.x, a.y - b.y); }
__device__ __forceinline__ float2 cmul(float2 a, float2 b) {
  return make_float2(fmaf(a.x, b.x, -a.y * b.y), fmaf(a.x, b.y, a.y * b.x));
}
__device__ __forceinline__ float2 cis(float ang) { float s, c; sincosf(ang, &s, &c); return make_float2(c, s); }

template<int S> __device__ __forceinline__ float2 rot90(float2 z) {
  return (S < 0) ? make_float2(z.y, -z.x) : make_float2(-z.y, z.x);
}
template<int S> __device__ __forceinline__ void dft4(float2& a, float2& b, float2& c, float2& d) {
  float2 t0 = cadd(a, c), t1 = csub(a, c), t2 = cadd(b, d), t3 = rot90<S>(csub(b, d));
  a = cadd(t0, t2); c = csub(t0, t2); b = cadd(t1, t3); d = csub(t1, t3);
}
template<int S> __device__ __forceinline__ void dft8(float2 v[8]) {
  const float RT = 0.70710678118654752f;
  const float SR = (S < 0) ? -RT : RT;
  float2 a0 = cadd(v[0], v[4]), a1 = cadd(v[1], v[5]), a2 = cadd(v[2], v[6]), a3 = cadd(v[3], v[7]);
  float2 b0 = csub(v[0], v[4]), b1 = csub(v[1], v[5]), b2 = csub(v[2], v[6]), b3 = csub(v[3], v[7]);
  b1 = cmul(b1, make_float2(RT, SR));
  b2 = rot90<S>(b2);
  b3 = cmul(b3, make_float2(-RT, SR));
  dft4<S>(a0, a1, a2, a3);
  dft4<S>(b0, b1, b2, b3);
  v[0] = a0; v[2] = a1; v[4] = a2; v[6] = a3;
  v[1] = b0; v[3] = b1; v[5] = b2; v[7] = b3;
}
// padded index: +1 element per 16 (<=2-way across all stage patterns)
__device__ __forceinline__ int sg(int e) { return e + (e >> 4); }

// ---------- packed-fp16 complex (channel pair per __half2 lane-slot) ----------
struct hc { __half2 re, im; };
__device__ __forceinline__ hc hcadd(hc a, hc b) { return { __hadd2(a.re, b.re), __hadd2(a.im, b.im) }; }
__device__ __forceinline__ hc hcsub(hc a, hc b) { return { __hsub2(a.re, b.re), __hsub2(a.im, b.im) }; }
template<int S> __device__ __forceinline__ hc hrot90(hc z) {       // *(-i) fwd
  hc r; if (S < 0) { r.re = z.im; r.im = __hneg2(z.re); } else { r.re = __hneg2(z.im); r.im = z.re; }
  return r;
}
__device__ __forceinline__ hc hcmul(hc v, __half2 wre, __half2 wim) {
  hc r;
  r.re = __hsub2(__hmul2(v.re, wre), __hmul2(v.im, wim));
  r.im = __hfma2(v.re, wim, __hmul2(v.im, wre));
  return r;
}
template<int S> __device__ __forceinline__ void hdft4(hc& a, hc& b, hc& c, hc& d) {
  hc t0 = hcadd(a, c), t1 = hcsub(a, c), t2 = hcadd(b, d), t3 = hrot90<S>(hcsub(b, d));
  a = hcadd(t0, t2); c = hcsub(t0, t2); b = hcadd(t1, t3); d = hcsub(t1, t3);
}
template<int S> __device__ __forceinline__ void hdft8(hc v[8]) {
  const float RT = 0.70710678118654752f;
  __half2 rt  = __float2half2_rn(RT);
  __half2 sr  = __float2half2_rn((S < 0) ? -RT : RT);
  __half2 nrt = __float2half2_rn(-RT);
  hc a0 = hcadd(v[0], v[4]), a1 = hcadd(v[1], v[5]), a2 = hcadd(v[2], v[6]), a3 = hcadd(v[3], v[7]);
  hc b0 = hcsub(v[0], v[4]), b1 = hcsub(v[1], v[5]), b2 = hcsub(v[2], v[6]), b3 = hcsub(v[3], v[7]);
  b1 = hcmul(b1, rt, sr);
  b2 = hrot90<S>(b2);
  b3 = hcmul(b3, nrt, sr);
  hdft4<S>(a0, a1, a2, a3);
  hdft4<S>(b0, b1, b2, b3);
  v[0] = a0; v[2] = a1; v[4] = a2; v[6] = a3;
  v[1] = b0; v[3] = b1; v[5] = b2; v[7] = b3;
}
__device__ __forceinline__ __half2 u2h(unsigned u) { return __builtin_bit_cast(__half2, u); }
__device__ __forceinline__ unsigned h2u(__half2 h) { return __builtin_bit_cast(unsigned, h); }

// ---------- kernel P: row-sequential pack q,k -> pair-packed fp16 slabs ----------
// Block (b, tile, j-half): reads 16 full 2KB rows of q,k (32KB contiguous per
// input), transposes in 34.8KB LDS, writes its disjoint 256B j-range per cq of
// the shared 64KB slab. Slab layout identical to r11/r12:
// f4 at (cq,jg) = [re01,im01,re23,im23], jg = h*16 + j.
__global__ __launch_bounds__(512) void pack_kernel(
    const float* __restrict__ q, const float* __restrict__ k,
    float4* __restrict__ z) {
  extern __shared__ float4 tile[];        // [128][17] = 2176 f4 = 34816 B
  int tid = threadIdx.x;
  int l = blockIdx.x;                     // ((b*64 + tl)<<1) | h
  int h = l & 1;
  int tl = (l >> 1) & 63;
  int b  = l >> 7;
  size_t rowbase = ((size_t)b * L_ + tl * 32 + h * 16) * 512;
  const float4* q4 = (const float4*)(q + rowbase);
  const float4* k4 = (const float4*)(k + rowbase);
  int cq = tid & 127;
  int j0 = tid >> 7;                      // 0..3
  float4 qv[4], kv[4];
#pragma unroll
  for (int pass = 0; pass < 4; ++pass) {
    int j = pass * 4 + j0;
    qv[pass] = q4[j * 128 + cq];
    kv[pass] = k4[j * 128 + cq];
  }
#pragma unroll
  for (int pass = 0; pass < 4; ++pass) {
    int j = pass * 4 + j0;
    float4 pk;
    ((__half2*)&pk)[0] = __float22half2_rn(make_float2(qv[pass].x, qv[pass].y));  // re01
    ((__half2*)&pk)[1] = __float22half2_rn(make_float2(kv[pass].x, kv[pass].y));  // im01
    ((__half2*)&pk)[2] = __float22half2_rn(make_float2(qv[pass].z, qv[pass].w));  // re23
    ((__half2*)&pk)[3] = __float22half2_rn(make_float2(kv[pass].z, kv[pass].w));  // im23
    tile[cq * 17 + j] = pk;
  }
  __syncthreads();
  float4* slab = z + (size_t)(l >> 1) * 4096;   // (b*64+tl)
#pragma unroll
  for (int pass = 0; pass < 4; ++pass) {
    int m = pass * 512 + tid;
    int c = m >> 4, j = m & 15;
    slab[c * 32 + h * 16 + j] = tile[c * 17 + j];
  }
}

// ---------- kernel F: packed-fp16 radix-8/8/8/4 DIF FFT + freq product ----------
// Block (b, cg): channels 4cg..4cg+3 as 2 packed pairs processed TOGETHER
// (dual register sets, one barrier per stage). 256 threads; 2 LDS regions of
// RS_ uint2. Digit-reversed storage pos=256k1+32k2+4k3+k4, f=k1+8k2+64k3+512k4.
__global__ __launch_bounds__(256, 4) void fft_corr_kernel(
    const float4* __restrict__ z, float2* __restrict__ part) {
  extern __shared__ uint2 dbuf[];         // 2 regions x RS_ uint2 = 34848 B
  int t = threadIdx.x;
  int j2 = t & 31, j3 = t & 3;
  int l = blockIdx.x;                     // b*128 + cg
  int cg = l & 127, b = l >> 7;
  const float4* zb = z + (size_t)b * 64 * 4096;

  // ---- staging: 64 tiles x 32 j of cq=cg -> 512B contiguous runs
#pragma unroll
  for (int it = 0; it < 8; ++it) {
    int m = it * 256 + t;
    int tl = m >> 5, j = m & 31;
    float4 pk = zb[(size_t)tl * 4096 + cg * 32 + j];
    int sp = sg(tl * 32 + j);
    dbuf[sp]       = make_uint2(__float_as_uint(pk.x), __float_as_uint(pk.y));
    dbuf[RS_ + sp] = make_uint2(__float_as_uint(pk.z), __float_as_uint(pk.w));
  }

  // twiddles: fp32 iterative chains -> broadcast half2
  __half2 t1re[7], t1im[7], t2re[7], t2im[7], t3re[7], t3im[7];
  {
    float2 w1 = cis(-6.283185307179586f * (float)t  / 2048.0f);
    float2 w2 = cis(-6.283185307179586f * (float)j2 / 256.0f);
    float2 w3 = cis(-6.283185307179586f * (float)j3 / 32.0f);
    float2 a1 = w1, a2 = w2, a3 = w3;
#pragma unroll
    for (int kk = 0; kk < 7; ++kk) {
      t1re[kk] = __float2half2_rn(a1.x); t1im[kk] = __float2half2_rn(a1.y);
      t2re[kk] = __float2half2_rn(a2.x); t2im[kk] = __float2half2_rn(a2.y);
      t3re[kk] = __float2half2_rn(a3.x); t3im[kk] = __float2half2_rn(a3.y);
      a1 = cmul(a1, w1); a2 = cmul(a2, w2); a3 = cmul(a3, w3);
    }
  }
  int base2 = (t >> 5) * 256 + j2;
  int base3 = (t >> 2) * 32 + j3;
  uint2* R0 = dbuf;
  uint2* R1 = dbuf + RS_;
  hc v0[8], v1[8];
  __syncthreads();                        // staging visible

  // ---- stage 1 (M=2048), both regions, in-place per thread
#pragma unroll
  for (int m = 0; m < 8; ++m) {
    uint2 u = R0[sg(t + 256 * m)]; v0[m].re = u2h(u.x); v0[m].im = u2h(u.y);
    u = R1[sg(t + 256 * m)];       v1[m].re = u2h(u.x); v1[m].im = u2h(u.y);
  }
  hdft8<-1>(v0); hdft8<-1>(v1);
#pragma unroll
  for (int kk = 1; kk < 8; ++kk) {
    v0[kk] = hcmul(v0[kk], t1re[kk - 1], t1im[kk - 1]);
    v1[kk] = hcmul(v1[kk], t1re[kk - 1], t1im[kk - 1]);
  }
#pragma unroll
  for (int kk = 0; kk < 8; ++kk) {
    R0[sg(t + 256 * kk)] = make_uint2(h2u(v0[kk].re), h2u(v0[kk].im));
    R1[sg(t + 256 * kk)] = make_uint2(h2u(v1[kk].re), h2u(v1[kk].im));
  }
  __syncthreads();
  // ---- stage 2 (M=256)
#pragma unroll
  for (int m = 0; m < 8; ++m) {
    uint2 u = R0[sg(base2 + 32 * m)]; v0[m].re = u2h(u.x); v0[m].im = u2h(u.y);
    u = R1[sg(base2 + 32 * m)];       v1[m].re = u2h(u.x); v1[m].im = u2h(u.y);
  }
  hdft8<-1>(v0); hdft8<-1>(v1);
#pragma unroll
  for (int kk = 1; kk < 8; ++kk) {
    v0[kk] = hcmul(v0[kk], t2re[kk - 1], t2im[kk - 1]);
    v1[kk] = hcmul(v1[kk], t2re[kk - 1], t2im[kk - 1]);
  }
#pragma unroll
  for (int kk = 0; kk < 8; ++kk) {
    R0[sg(base2 + 32 * kk)] = make_uint2(h2u(v0[kk].re), h2u(v0[kk].im));
    R1[sg(base2 + 32 * kk)] = make_uint2(h2u(v1[kk].re), h2u(v1[kk].im));
  }
  __syncthreads();
  // ---- stage 3 (M=32)
#pragma unroll
  for (int m = 0; m < 8; ++m) {
    uint2 u = R0[sg(base3 + 4 * m)]; v0[m].re = u2h(u.x); v0[m].im = u2h(u.y);
    u = R1[sg(base3 + 4 * m)];       v1[m].re = u2h(u.x); v1[m].im = u2h(u.y);
  }
  hdft8<-1>(v0); hdft8<-1>(v1);
#pragma unroll
  for (int kk = 1; kk < 8; ++kk) {
    v0[kk] = hcmul(v0[kk], t3re[kk - 1], t3im[kk - 1]);
    v1[kk] = hcmul(v1[kk], t3re[kk - 1], t3im[kk - 1]);
  }
#pragma unroll
  for (int kk = 0; kk < 8; ++kk) {
    R0[sg(base3 + 4 * kk)] = make_uint2(h2u(v0[kk].re), h2u(v0[kk].im));
    R1[sg(base3 + 4 * kk)] = make_uint2(h2u(v1[kk].re), h2u(v1[kk].im));
  }
  __syncthreads();
  // ---- stage 4 (M=4 radix-4, thread-private quads 8t..8t+7)
#pragma unroll
  for (int kk = 0; kk < 8; ++kk) {
    uint2 u = R0[sg(8 * t + kk)]; v0[kk].re = u2h(u.x); v0[kk].im = u2h(u.y);
    u = R1[sg(8 * t + kk)];       v1[kk].re = u2h(u.x); v1[kk].im = u2h(u.y);
  }
  hdft4<-1>(v0[0], v0[1], v0[2], v0[3]); hdft4<-1>(v0[4], v0[5], v0[6], v0[7]);
  hdft4<-1>(v1[0], v1[1], v1[2], v1[3]); hdft4<-1>(v1[4], v1[5], v1[6], v1[7]);
#pragma unroll
  for (int kk = 0; kk < 8; ++kk) {
    R0[sg(8 * t + kk)] = make_uint2(h2u(v0[kk].re), h2u(v0[kk].im));
    R1[sg(8 * t + kk)] = make_uint2(h2u(v1[kk].re), h2u(v1[kk].im));
  }
  __syncthreads();
  // ---- product: P = Qf*conj(Kf), -f by digit arithmetic; fp32 accumulate
  // all 4 channels (2 per region).
  float2 acc[8];
#pragma unroll
  for (int kk = 0; kk < 8; ++kk) {
    int pos = 8 * t + kk;
    int f  = ((pos >> 8) & 7) | (((pos >> 5) & 7) << 3) | (((pos >> 2) & 7) << 6) | ((pos & 3) << 9);
    int fp = (2048 - f) & 2047;
    int pp = ((fp & 7) << 8) | (((fp >> 3) & 7) << 5) | (((fp >> 6) & 7) << 2) | ((fp >> 9) & 3);
    float sx = 0.f, sy = 0.f;
    {
      uint2 ub = R0[sg(pp)];
      __half2 bre = u2h(ub.x), bim = u2h(ub.y);
      float ar0 = __low2float(v0[kk].re),  ar1 = __high2float(v0[kk].re);
      float ai0 = __low2float(v0[kk].im),  ai1 = __high2float(v0[kk].im);
      float br0 = __low2float(bre),        br1 = __high2float(bre);
      float bi0 = __low2float(bim),        bi1 = __high2float(bim);
      sx += (br0 * ai0 + bi0 * ar0) + (br1 * ai1 + bi1 * ar1);
      sy += (ar0 * ar0 + ai0 * ai0 - br0 * br0 - bi0 * bi0)
          + (ar1 * ar1 + ai1 * ai1 - br1 * br1 - bi1 * bi1);
    }
    {
      uint2 ub = R1[sg(pp)];
      __half2 bre = u2h(ub.x), bim = u2h(ub.y);
      float ar0 = __low2float(v1[kk].re),  ar1 = __high2float(v1[kk].re);
      float ai0 = __low2float(v1[kk].im),  ai1 = __high2float(v1[kk].im);
      float br0 = __low2float(bre),        br1 = __high2float(bre);
      float bi0 = __low2float(bim),        bi1 = __high2float(bim);
      sx += (br0 * ai0 + bi0 * ar0) + (br1 * ai1 + bi1 * ar1);
      sy += (ar0 * ar0 + ai0 * ai0 - br0 * br0 - bi0 * bi0)
          + (ar1 * ar1 + ai1 * ai1 - br1 * br1 - bi1 * bi1);
    }
    acc[kk] = make_float2(0.5f * sx, 0.25f * sy);
  }
  __syncthreads();                        // product reads of R0/R1 complete
  // park fp32 sums into region 0, then coalesced 256-wide store.
  {
    float2* pk0 = (float2*)dbuf;
#pragma unroll
    for (int kk = 0; kk < 8; ++kk) pk0[sg(8 * t + kk)] = acc[kk];
  }
  __syncthreads();
  {
    const float2* pk0 = (const float2*)dbuf;
    float2* prow = part + (size_t)l * L_;
#pragma unroll
    for (int m = 0; m < 8; ++m) {
      int p = t + 256 * m;
      prow[p] = pk0[sg(p)];
    }
  }
}

// ---------- kernel R: sum 128 partial rows -> S[b][p] ----------
__global__ __launch_bounds__(256) void reduce_S_kernel(
    const float2* __restrict__ part, float2* __restrict__ S) {
  int idx = blockIdx.x * 256 + threadIdx.x;   // 0..32767 = [b][p]
  int p = idx & 2047;
  int b = idx >> 11;
  float2 s = make_float2(0.f, 0.f);
#pragma unroll 4
  for (int i = 0; i < 128; ++i) {
    float2 vv = part[(size_t)(b * 128 + i) * L_ + p];
    s.x += vv.x; s.y += vv.y;
  }
  S[idx] = s;
}

// ---------- kernel I: mirrored DIT inverse (digit-reversed in, natural out) ----------
__global__ __launch_bounds__(256) void ifft_kernel(
    const float2* __restrict__ S, float* __restrict__ mv) {
  __shared__ float2 buf[2176];
  int t = threadIdx.x, b = blockIdx.x;
  int j2 = t & 31, j3 = t & 3;
  float2 tw1[7], tw2[7], tw3[7];
  {
    float2 w1 = cis(6.283185307179586f * (float)t  / 2048.0f);
    float2 w2 = cis(6.283185307179586f * (float)j2 / 256.0f);
    float2 w3 = cis(6.283185307179586f * (float)j3 / 32.0f);
    tw1[0] = w1; tw2[0] = w2; tw3[0] = w3;
#pragma unroll
    for (int kk = 1; kk < 7; ++kk) {
      tw1[kk] = cmul(tw1[kk - 1], w1);
      tw2[kk] = cmul(tw2[kk - 1], w2);
      tw3[kk] = cmul(tw3[kk - 1], w3);
    }
  }
  int base2 = (t >> 5) * 256 + j2;
  int base3 = (t >> 2) * 32 + j3;
  // stage A: M=4 DFT (no twiddle), quads 8t..8t+7
  float2 u[8];
  {
    const float4* rp = (const float4*)(S + (size_t)b * L_);
#pragma unroll
    for (int m = 0; m < 4; ++m) {
      float4 f = rp[4 * t + m];
      u[2 * m]     = make_float2(f.x, f.y);
      u[2 * m + 1] = make_float2(f.z, f.w);
    }
  }
  dft4<1>(u[0], u[1], u[2], u[3]);
  dft4<1>(u[4], u[5], u[6], u[7]);
#pragma unroll
  for (int kk = 0; kk < 8; ++kk) buf[sg(8 * t + kk)] = u[kk];
  __syncthreads();
  // stage B: M=32
  float2 v[8];
#pragma unroll
  for (int kk = 0; kk < 8; ++kk) v[kk] = buf[sg(base3 + 4 * kk)];
#pragma unroll
  for (int kk = 1; kk < 8; ++kk) v[kk] = cmul(v[kk], tw3[kk - 1]);
  dft8<1>(v);
  __syncthreads();
#pragma unroll
  for (int m = 0; m < 8; ++m) buf[sg(base3 + 4 * m)] = v[m];
  __syncthreads();
  // stage C: M=256
#pragma unroll
  for (int kk = 0; kk < 8; ++kk) v[kk] = buf[sg(base2 + 32 * kk)];
#pragma unroll
  for (int kk = 1; kk < 8; ++kk) v[kk] = cmul(v[kk], tw2[kk - 1]);
  dft8<1>(v);
  __syncthreads();
#pragma unroll
  for (int m = 0; m < 8; ++m) buf[sg(base2 + 32 * m)] = v[m];
  __syncthreads();
  // stage D: M=2048 -> natural order
#pragma unroll
  for (int kk = 0; kk < 8; ++kk) v[kk] = buf[sg(t + 256 * kk)];
#pragma unroll
  for (int kk = 1; kk < 8; ++kk) v[kk] = cmul(v[kk], tw1[kk - 1]);
  dft8<1>(v);
  const float scale = 1.0f / (2048.0f * 512.0f);  // 1/N * mean over H*E
#pragma unroll
  for (int m = 0; m < 8; ++m) mv[b * L_ + t + 256 * m] = v[m].x * scale;
}

// ---------- kernel K: batch-mean top-7 + per-batch softmax weights ----------
__global__ __launch_bounds__(256) void topk_kernel(
    const float* __restrict__ mv, int* __restrict__ topk, float* __restrict__ wts) {
  __shared__ float av[2048];
  __shared__ float rv[256];
  __shared__ int   ri[256];
  __shared__ int   sidx[K_];
  int tid = threadIdx.x;
  for (int d = tid; d < 2048; d += 256) {
    float s = 0.f;
#pragma unroll
    for (int b = 0; b < B_; ++b) s += mv[b * L_ + d];
    av[d] = s;
  }
  __syncthreads();
  for (int kk = 0; kk < K_; ++kk) {
    float bv = -INFINITY; int bi = 0;
    for (int d = tid; d < 2048; d += 256) {
      float vv = av[d];
      if (vv > bv) { bv = vv; bi = d; }
    }
    rv[tid] = bv; ri[tid] = bi;
    __syncthreads();
    for (int off = 128; off > 0; off >>= 1) {
      if (tid < off) {
        float v2 = rv[tid + off]; int i2 = ri[tid + off];
        if (v2 > rv[tid] || (v2 == rv[tid] && i2 < ri[tid])) { rv[tid] = v2; ri[tid] = i2; }
      }
      __syncthreads();
    }
    if (tid == 0) { sidx[kk] = ri[0]; av[ri[0]] = -INFINITY; }
    __syncthreads();
  }
  if (tid < K_) topk[tid] = sidx[tid];
  if (tid < B_) {
    float xk[K_], m = -INFINITY;
#pragma unroll
    for (int kk = 0; kk < K_; ++kk) { xk[kk] = mv[tid * L_ + sidx[kk]]; m = fmaxf(m, xk[kk]); }
    float s = 0.f;
#pragma unroll
    for (int kk = 0; kk < K_; ++kk) { xk[kk] = expf(xk[kk] - m); s += xk[kk]; }
#pragma unroll
    for (int kk = 0; kk < K_; ++kk) wts[tid * K_ + kk] = xk[kk] / s;
  }
}

// ---------- kernel G: out[b,t,h,e] = sum_k w[b,k] * v[b,(t+d_k)%L,h,e] ----------
__global__ __launch_bounds__(256) void aggregate_kernel(
    const float4* __restrict__ v4, const int* __restrict__ topk,
    const float* __restrict__ wts, float4* __restrict__ out4) {
  __shared__ int   sidx[K_];
  __shared__ float sw[B_][K_];
  int tid = threadIdx.x;
  if (tid < K_) sidx[tid] = topk[tid];
  if (tid < B_ * K_) sw[tid / K_][tid % K_] = wts[tid];
  __syncthreads();
  int idx = blockIdx.x * 256 + tid;
  int c4  = idx & 127;
  int row = idx >> 7;
  int t   = row & (L_ - 1);
  int b   = row >> 11;
  float4 acc = make_float4(0.f, 0.f, 0.f, 0.f);
#pragma unroll
  for (int kk = 0; kk < K_; ++kk) {
    int s = t + sidx[kk];
    if (s >= L_) s -= L_;
    float w = sw[b][kk];
    float4 val = v4[((size_t)(b * L_ + s) << 7) + c4];
    acc.x += w * val.x; acc.y += w * val.y;
    acc.z += w * val.z; acc.w += w * val.w;
  }
  out4[idx] = acc;
}

extern "C" void kernel_launch(void* const* d_in, const int* in_sizes, int n_in,
                              void* d_out, int out_size, void* d_ws, size_t ws_size,
                              hipStream_t stream) {
  const float* q = (const float*)d_in[0];
  const float* k = (const float*)d_in[1];
  const float* v = (const float*)d_in[2];
  float* out = (float*)d_out;

  char* ws = (char*)d_ws;
  float4* z    = (float4*)(ws + Z_OFF);
  float2* part = (float2*)(ws + PART_OFF);
  float2* S    = (float2*)(ws + S_OFF);
  float*  mv   = (float*) (ws + MV_OFF);
  int*    topk = (int*)   (ws + TK_OFF);
  float*  wts  = (float*) (ws + W_OFF);

  pack_kernel<<<B_ * 64 * 2, 512, 2176 * sizeof(float4), stream>>>(q, k, z);
  fft_corr_kernel<<<B_ * 128, 256, 2 * RS_ * sizeof(uint2), stream>>>(z, part);
  reduce_S_kernel<<<(B_ * L_) / 256, 256, 0, stream>>>(part, S);
  ifft_kernel<<<B_, 256, 0, stream>>>(S, mv);
  topk_kernel<<<1, 256, 0, stream>>>(mv, topk, wts);
  aggregate_kernel<<<(B_ * L_ * H_ * E_ / 4) / 256, 256, 0, stream>>>(
      (const float4*)v, topk, wts, (float4*)out);
}

// Round 14
// 153.245 us; speedup vs baseline: 1.1945x; 1.0125x over previous
//
#include <hip/hip_runtime.h>
#include <hip/hip_bf16.h>
#include <hip/hip_fp16.h>
#include <math.h>

// AutoCorrelation (Autoformer). B=16, L=2048, H=8, E=64, fp32.
// Round 14: barrier-free pack. The 32x128-f4 tile transpose is done as 8x8-f4
// wave-local subtiles via lane-permute (__shfl) -- zero LDS, zero barriers,
// every wave streams independently (r13's block-wide load/store phase barrier
// was the last candidate limiter; occupancy now caps at 32 waves/CU).
// Slab layout byte-identical to r13; fft/reduce/ifft/topk/aggregate
// byte-identical to validated r13.

#define B_ 16
#define L_ 2048
#define H_ 8
#define E_ 64
#define K_ 7
#define RS_ 2178          // region stride in uint2 (8B) units; sg(2047)=2174 < RS_

// ---------- workspace layout ----------
#define Z_OFF    0ull                              // fp16 slabs: 1024 x 64KB = 64 MiB
#define PART_OFF 67108864ull                       // float2[2048][2048] = 32 MiB
#define S_OFF    (PART_OFF + 33554432ull)          // float2[16][2048] = 256 KiB
#define MV_OFF   (S_OFF + 262144ull)               // float [B][L]
#define TK_OFF   (MV_OFF + 131072ull)              // int[7]
#define W_OFF    (TK_OFF + 64ull)                  // float[16][7]

// ---------- fp32 complex helpers (ifft/twiddle gen) ----------
__device__ __forceinline__ float2 cadd(float2 a, float2 b) { return make_float2(a.x + b.x, a.y + b.y); }
__device__ __forceinline__ float2 csub(float2 a, float2 b) { return make_float2(a.x - b.x, a.y - b.y); }
__device__ __forceinline__ float2 cmul(float2 a, float2 b) {
  return make_float2(fmaf(a.x, b.x, -a.y * b.y), fmaf(a.x, b.y, a.y * b.x));
}
__device__ __forceinline__ float2 cis(float ang) { float s, c; sincosf(ang, &s, &c); return make_float2(c, s); }

template<int S> __device__ __forceinline__ float2 rot90(float2 z) {
  return (S < 0) ? make_float2(z.y, -z.x) : make_float2(-z.y, z.x);
}
template<int S> __device__ __forceinline__ void dft4(float2& a, float2& b, float2& c, float2& d) {
  float2 t0 = cadd(a, c), t1 = csub(a, c), t2 = cadd(b, d), t3 = rot90<S>(csub(b, d));
  a = cadd(t0, t2); c = csub(t0, t2); b = cadd(t1, t3); d = csub(t1, t3);
}
template<int S> __device__ __forceinline__ void dft8(float2 v[8]) {
  const float RT = 0.70710678118654752f;
  const float SR = (S < 0) ? -RT : RT;
  float2 a0 = cadd(v[0], v[4]), a1 = cadd(v[1], v[5]), a2 = cadd(v[2], v[6]), a3 = cadd(v[3], v[7]);
  float2 b0 = csub(v[0], v[4]), b1 = csub(v[1], v[5]), b2 = csub(v[2], v[6]), b3 = csub(v[3], v[7]);
  b1 = cmul(b1, make_float2(RT, SR));
  b2 = rot90<S>(b2);
  b3 = cmul(b3, make_float2(-RT, SR));
  dft4<S>(a0, a1, a2, a3);
  dft4<S>(b0, b1, b2, b3);
  v[0] = a0; v[2] = a1; v[4] = a2; v[6] = a3;
  v[1] = b0; v[3] = b1; v[5] = b2; v[7] = b3;
}
// padded index: +1 element per 16 (<=2-way across all stage patterns)
__device__ __forceinline__ int sg(int e) { return e + (e >> 4); }

// ---------- packed-fp16 complex (channel pair per __half2 lane-slot) ----------
struct hc { __half2 re, im; };
__device__ __forceinline__ hc hcadd(hc a, hc b) { return { __hadd2(a.re, b.re), __hadd2(a.im, b.im) }; }
__device__ __forceinline__ hc hcsub(hc a, hc b) { return { __hsub2(a.re, b.re), __hsub2(a.im, b.im) }; }
template<int S> __device__ __forceinline__ hc hrot90(hc z) {       // *(-i) fwd
  hc r; if (S < 0) { r.re = z.im; r.im = __hneg2(z.re); } else { r.re = __hneg2(z.im); r.im = z.re; }
  return r;
}
__device__ __forceinline__ hc hcmul(hc v, __half2 wre, __half2 wim) {
  hc r;
  r.re = __hsub2(__hmul2(v.re, wre), __hmul2(v.im, wim));
  r.im = __hfma2(v.re, wim, __hmul2(v.im, wre));
  return r;
}
template<int S> __device__ __forceinline__ void hdft4(hc& a, hc& b, hc& c, hc& d) {
  hc t0 = hcadd(a, c), t1 = hcsub(a, c), t2 = hcadd(b, d), t3 = hrot90<S>(hcsub(b, d));
  a = hcadd(t0, t2); c = hcsub(t0, t2); b = hcadd(t1, t3); d = hcsub(t1, t3);
}
template<int S> __device__ __forceinline__ void hdft8(hc v[8]) {
  const float RT = 0.70710678118654752f;
  __half2 rt  = __float2half2_rn(RT);
  __half2 sr  = __float2half2_rn((S < 0) ? -RT : RT);
  __half2 nrt = __float2half2_rn(-RT);
  hc a0 = hcadd(v[0], v[4]), a1 = hcadd(v[1], v[5]), a2 = hcadd(v[2], v[6]), a3 = hcadd(v[3], v[7]);
  hc b0 = hcsub(v[0], v[4]), b1 = hcsub(v[1], v[5]), b2 = hcsub(v[2], v[6]), b3 = hcsub(v[3], v[7]);
  b1 = hcmul(b1, rt, sr);
  b2 = hrot90<S>(b2);
  b3 = hcmul(b3, nrt, sr);
  hdft4<S>(a0, a1, a2, a3);
  hdft4<S>(b0, b1, b2, b3);
  v[0] = a0; v[2] = a1; v[4] = a2; v[6] = a3;
  v[1] = b0; v[3] = b1; v[5] = b2; v[7] = b3;
}
__device__ __forceinline__ __half2 u2h(unsigned u) { return __builtin_bit_cast(__half2, u); }
__device__ __forceinline__ unsigned h2u(__half2 h) { return __builtin_bit_cast(unsigned, h); }

// ---------- kernel P: barrier-free pack q,k -> pair-packed fp16 slabs ----------
// Block (b, tile) = 512 threads = 8 waves, zero LDS. Each wave transposes 8
// independent 8x8-f4 subtiles via lane-permute: read c-major (8x128B runs),
// __shfl lane swap (r,c)->(c,r), write r-major (8x128B runs). Slab layout
// identical to r11-r13: f4 at (cq,j) = [re01,im01,re23,im23].
__global__ __launch_bounds__(512) void pack_kernel(
    const float* __restrict__ q, const float* __restrict__ k,
    float4* __restrict__ z) {
  int tid = threadIdx.x;
  int l = blockIdx.x;                     // b*64 + tl
  int tl = l & 63, b = l >> 6;
  size_t rowbase = ((size_t)b * L_ + tl * 32) * 512;   // floats
  const float4* q4 = (const float4*)(q + rowbase);
  const float4* k4 = (const float4*)(k + rowbase);
  float4* slab = z + (size_t)l * 4096;
  int w = tid >> 6;                       // wave 0..7
  int lane = tid & 63;
  int r = lane >> 3, c = lane & 7;        // read roles
  int srcLane = ((lane & 7) << 3) | (lane >> 3);
#pragma unroll
  for (int i = 0; i < 8; ++i) {
    int s = w * 8 + i;                    // subtile 0..63
    int tr = s & 3, cc = s >> 2;          // tau-octet, cq-octet
    int ridx = (tr * 8 + r) * 128 + cc * 8 + c;
    float4 qv = q4[ridx];
    float4 kv = k4[ridx];
    float4 pk;
    ((__half2*)&pk)[0] = __float22half2_rn(make_float2(qv.x, qv.y));  // re01
    ((__half2*)&pk)[1] = __float22half2_rn(make_float2(kv.x, kv.y));  // im01
    ((__half2*)&pk)[2] = __float22half2_rn(make_float2(qv.z, qv.w));  // re23
    ((__half2*)&pk)[3] = __float22half2_rn(make_float2(kv.z, kv.w));  // im23
    // 8x8 transpose across lanes: dest lane (8c+r) pulls from lane (8r+c)
    float4 tp;
    tp.x = __shfl(pk.x, srcLane, 64);
    tp.y = __shfl(pk.y, srcLane, 64);
    tp.z = __shfl(pk.z, srcLane, 64);
    tp.w = __shfl(pk.w, srcLane, 64);
    // lane now holds element (tau = tr*8 + (lane&7), cq = cc*8 + (lane>>3))
    slab[(cc * 8 + (lane >> 3)) * 32 + tr * 8 + (lane & 7)] = tp;
  }
}

// ---------- kernel F: packed-fp16 radix-8/8/8/4 DIF FFT + freq product ----------
// Block (b, cg): channels 4cg..4cg+3 as 2 packed pairs processed TOGETHER
// (dual register sets, one barrier per stage). 256 threads; 2 LDS regions of
// RS_ uint2. Digit-reversed storage pos=256k1+32k2+4k3+k4, f=k1+8k2+64k3+512k4.
__global__ __launch_bounds__(256, 4) void fft_corr_kernel(
    const float4* __restrict__ z, float2* __restrict__ part) {
  extern __shared__ uint2 dbuf[];         // 2 regions x RS_ uint2 = 34848 B
  int t = threadIdx.x;
  int j2 = t & 31, j3 = t & 3;
  int l = blockIdx.x;                     // b*128 + cg
  int cg = l & 127, b = l >> 7;
  const float4* zb = z + (size_t)b * 64 * 4096;

  // ---- staging: 64 tiles x 32 j of cq=cg -> 512B contiguous runs
#pragma unroll
  for (int it = 0; it < 8; ++it) {
    int m = it * 256 + t;
    int tl = m >> 5, j = m & 31;
    float4 pk = zb[(size_t)tl * 4096 + cg * 32 + j];
    int sp = sg(tl * 32 + j);
    dbuf[sp]       = make_uint2(__float_as_uint(pk.x), __float_as_uint(pk.y));
    dbuf[RS_ + sp] = make_uint2(__float_as_uint(pk.z), __float_as_uint(pk.w));
  }

  // twiddles: fp32 iterative chains -> broadcast half2
  __half2 t1re[7], t1im[7], t2re[7], t2im[7], t3re[7], t3im[7];
  {
    float2 w1 = cis(-6.283185307179586f * (float)t  / 2048.0f);
    float2 w2 = cis(-6.283185307179586f * (float)j2 / 256.0f);
    float2 w3 = cis(-6.283185307179586f * (float)j3 / 32.0f);
    float2 a1 = w1, a2 = w2, a3 = w3;
#pragma unroll
    for (int kk = 0; kk < 7; ++kk) {
      t1re[kk] = __float2half2_rn(a1.x); t1im[kk] = __float2half2_rn(a1.y);
      t2re[kk] = __float2half2_rn(a2.x); t2im[kk] = __float2half2_rn(a2.y);
      t3re[kk] = __float2half2_rn(a3.x); t3im[kk] = __float2half2_rn(a3.y);
      a1 = cmul(a1, w1); a2 = cmul(a2, w2); a3 = cmul(a3, w3);
    }
  }
  int base2 = (t >> 5) * 256 + j2;
  int base3 = (t >> 2) * 32 + j3;
  uint2* R0 = dbuf;
  uint2* R1 = dbuf + RS_;
  hc v0[8], v1[8];
  __syncthreads();                        // staging visible

  // ---- stage 1 (M=2048), both regions, in-place per thread
#pragma unroll
  for (int m = 0; m < 8; ++m) {
    uint2 u = R0[sg(t + 256 * m)]; v0[m].re = u2h(u.x); v0[m].im = u2h(u.y);
    u = R1[sg(t + 256 * m)];       v1[m].re = u2h(u.x); v1[m].im = u2h(u.y);
  }
  hdft8<-1>(v0); hdft8<-1>(v1);
#pragma unroll
  for (int kk = 1; kk < 8; ++kk) {
    v0[kk] = hcmul(v0[kk], t1re[kk - 1], t1im[kk - 1]);
    v1[kk] = hcmul(v1[kk], t1re[kk - 1], t1im[kk - 1]);
  }
#pragma unroll
  for (int kk = 0; kk < 8; ++kk) {
    R0[sg(t + 256 * kk)] = make_uint2(h2u(v0[kk].re), h2u(v0[kk].im));
    R1[sg(t + 256 * kk)] = make_uint2(h2u(v1[kk].re), h2u(v1[kk].im));
  }
  __syncthreads();
  // ---- stage 2 (M=256)
#pragma unroll
  for (int m = 0; m < 8; ++m) {
    uint2 u = R0[sg(base2 + 32 * m)]; v0[m].re = u2h(u.x); v0[m].im = u2h(u.y);
    u = R1[sg(base2 + 32 * m)];       v1[m].re = u2h(u.x); v1[m].im = u2h(u.y);
  }
  hdft8<-1>(v0); hdft8<-1>(v1);
#pragma unroll
  for (int kk = 1; kk < 8; ++kk) {
    v0[kk] = hcmul(v0[kk], t2re[kk - 1], t2im[kk - 1]);
    v1[kk] = hcmul(v1[kk], t2re[kk - 1], t2im[kk - 1]);
  }
#pragma unroll
  for (int kk = 0; kk < 8; ++kk) {
    R0[sg(base2 + 32 * kk)] = make_uint2(h2u(v0[kk].re), h2u(v0[kk].im));
    R1[sg(base2 + 32 * kk)] = make_uint2(h2u(v1[kk].re), h2u(v1[kk].im));
  }
  __syncthreads();
  // ---- stage 3 (M=32)
#pragma unroll
  for (int m = 0; m < 8; ++m) {
    uint2 u = R0[sg(base3 + 4 * m)]; v0[m].re = u2h(u.x); v0[m].im = u2h(u.y);
    u = R1[sg(base3 + 4 * m)];       v1[m].re = u2h(u.x); v1[m].im = u2h(u.y);
  }
  hdft8<-1>(v0); hdft8<-1>(v1);
#pragma unroll
  for (int kk = 1; kk < 8; ++kk) {
    v0[kk] = hcmul(v0[kk], t3re[kk - 1], t3im[kk - 1]);
    v1[kk] = hcmul(v1[kk], t3re[kk - 1], t3im[kk - 1]);
  }
#pragma unroll
  for (int kk = 0; kk < 8; ++kk) {
    R0[sg(base3 + 4 * kk)] = make_uint2(h2u(v0[kk].re), h2u(v0[kk].im));
    R1[sg(base3 + 4 * kk)] = make_uint2(h2u(v1[kk].re), h2u(v1[kk].im));
  }
  __syncthreads();
  // ---- stage 4 (M=4 radix-4, thread-private quads 8t..8t+7)
#pragma unroll
  for (int kk = 0; kk < 8; ++kk) {
    uint2 u = R0[sg(8 * t + kk)]; v0[kk].re = u2h(u.x); v0[kk].im = u2h(u.y);
    u = R1[sg(8 * t + kk)];       v1[kk].re = u2h(u.x); v1[kk].im = u2h(u.y);
  }
  hdft4<-1>(v0[0], v0[1], v0[2], v0[3]); hdft4<-1>(v0[4], v0[5], v0[6], v0[7]);
  hdft4<-1>(v1[0], v1[1], v1[2], v1[3]); hdft4<-1>(v1[4], v1[5], v1[6], v1[7]);
#pragma unroll
  for (int kk = 0; kk < 8; ++kk) {
    R0[sg(8 * t + kk)] = make_uint2(h2u(v0[kk].re), h2u(v0[kk].im));
    R1[sg(8 * t + kk)] = make_uint2(h2u(v1[kk].re), h2u(v1[kk].im));
  }
  __syncthreads();
  // ---- product: P = Qf*conj(Kf), -f by digit arithmetic; fp32 accumulate
  // all 4 channels (2 per region).
  float2 acc[8];
#pragma unroll
  for (int kk = 0; kk < 8; ++kk) {
    int pos = 8 * t + kk;
    int f  = ((pos >> 8) & 7) | (((pos >> 5) & 7) << 3) | (((pos >> 2) & 7) << 6) | ((pos & 3) << 9);
    int fp = (2048 - f) & 2047;
    int pp = ((fp & 7) << 8) | (((fp >> 3) & 7) << 5) | (((fp >> 6) & 7) << 2) | ((fp >> 9) & 3);
    float sx = 0.f, sy = 0.f;
    {
      uint2 ub = R0[sg(pp)];
      __half2 bre = u2h(ub.x), bim = u2h(ub.y);
      float ar0 = __low2float(v0[kk].re),  ar1 = __high2float(v0[kk].re);
      float ai0 = __low2float(v0[kk].im),  ai1 = __high2float(v0[kk].im);
      float br0 = __low2float(bre),        br1 = __high2float(bre);
      float bi0 = __low2float(bim),        bi1 = __high2float(bim);
      sx += (br0 * ai0 + bi0 * ar0) + (br1 * ai1 + bi1 * ar1);
      sy += (ar0 * ar0 + ai0 * ai0 - br0 * br0 - bi0 * bi0)
          + (ar1 * ar1 + ai1 * ai1 - br1 * br1 - bi1 * bi1);
    }
    {
      uint2 ub = R1[sg(pp)];
      __half2 bre = u2h(ub.x), bim = u2h(ub.y);
      float ar0 = __low2float(v1[kk].re),  ar1 = __high2float(v1[kk].re);
      float ai0 = __low2float(v1[kk].im),  ai1 = __high2float(v1[kk].im);
      float br0 = __low2float(bre),        br1 = __high2float(bre);
      float bi0 = __low2float(bim),        bi1 = __high2float(bim);
      sx += (br0 * ai0 + bi0 * ar0) + (br1 * ai1 + bi1 * ar1);
      sy += (ar0 * ar0 + ai0 * ai0 - br0 * br0 - bi0 * bi0)
          + (ar1 * ar1 + ai1 * ai1 - br1 * br1 - bi1 * bi1);
    }
    acc[kk] = make_float2(0.5f * sx, 0.25f * sy);
  }
  __syncthreads();                        // product reads of R0/R1 complete
  // park fp32 sums into region 0, then coalesced 256-wide store.
  {
    float2* pk0 = (float2*)dbuf;
#pragma unroll
    for (int kk = 0; kk < 8; ++kk) pk0[sg(8 * t + kk)] = acc[kk];
  }
  __syncthreads();
  {
    const float2* pk0 = (const float2*)dbuf;
    float2* prow = part + (size_t)l * L_;
#pragma unroll
    for (int m = 0; m < 8; ++m) {
      int p = t + 256 * m;
      prow[p] = pk0[sg(p)];
    }
  }
}

// ---------- kernel R: sum 128 partial rows -> S[b][p] ----------
__global__ __launch_bounds__(256) void reduce_S_kernel(
    const float2* __restrict__ part, float2* __restrict__ S) {
  int idx = blockIdx.x * 256 + threadIdx.x;   // 0..32767 = [b][p]
  int p = idx & 2047;
  int b = idx >> 11;
  float2 s = make_float2(0.f, 0.f);
#pragma unroll 4
  for (int i = 0; i < 128; ++i) {
    float2 vv = part[(size_t)(b * 128 + i) * L_ + p];
    s.x += vv.x; s.y += vv.y;
  }
  S[idx] = s;
}

// ---------- kernel I: mirrored DIT inverse (digit-reversed in, natural out) ----------
__global__ __launch_bounds__(256) void ifft_kernel(
    const float2* __restrict__ S, float* __restrict__ mv) {
  __shared__ float2 buf[2176];
  int t = threadIdx.x, b = blockIdx.x;
  int j2 = t & 31, j3 = t & 3;
  float2 tw1[7], tw2[7], tw3[7];
  {
    float2 w1 = cis(6.283185307179586f * (float)t  / 2048.0f);
    float2 w2 = cis(6.283185307179586f * (float)j2 / 256.0f);
    float2 w3 = cis(6.283185307179586f * (float)j3 / 32.0f);
    tw1[0] = w1; tw2[0] = w2; tw3[0] = w3;
#pragma unroll
    for (int kk = 1; kk < 7; ++kk) {
      tw1[kk] = cmul(tw1[kk - 1], w1);
      tw2[kk] = cmul(tw2[kk - 1], w2);
      tw3[kk] = cmul(tw3[kk - 1], w3);
    }
  }
  int base2 = (t >> 5) * 256 + j2;
  int base3 = (t >> 2) * 32 + j3;
  // stage A: M=4 DFT (no twiddle), quads 8t..8t+7
  float2 u[8];
  {
    const float4* rp = (const float4*)(S + (size_t)b * L_);
#pragma unroll
    for (int m = 0; m < 4; ++m) {
      float4 f = rp[4 * t + m];
      u[2 * m]     = make_float2(f.x, f.y);
      u[2 * m + 1] = make_float2(f.z, f.w);
    }
  }
  dft4<1>(u[0], u[1], u[2], u[3]);
  dft4<1>(u[4], u[5], u[6], u[7]);
#pragma unroll
  for (int kk = 0; kk < 8; ++kk) buf[sg(8 * t + kk)] = u[kk];
  __syncthreads();
  // stage B: M=32
  float2 v[8];
#pragma unroll
  for (int kk = 0; kk < 8; ++kk) v[kk] = buf[sg(base3 + 4 * kk)];
#pragma unroll
  for (int kk = 1; kk < 8; ++kk) v[kk] = cmul(v[kk], tw3[kk - 1]);
  dft8<1>(v);
  __syncthreads();
#pragma unroll
  for (int m = 0; m < 8; ++m) buf[sg(base3 + 4 * m)] = v[m];
  __syncthreads();
  // stage C: M=256
#pragma unroll
  for (int kk = 0; kk < 8; ++kk) v[kk] = buf[sg(base2 + 32 * kk)];
#pragma unroll
  for (int kk = 1; kk < 8; ++kk) v[kk] = cmul(v[kk], tw2[kk - 1]);
  dft8<1>(v);
  __syncthreads();
#pragma unroll
  for (int m = 0; m < 8; ++m) buf[sg(base2 + 32 * m)] = v[m];
  __syncthreads();
  // stage D: M=2048 -> natural order
#pragma unroll
  for (int kk = 0; kk < 8; ++kk) v[kk] = buf[sg(t + 256 * kk)];
#pragma unroll
  for (int kk = 1; kk < 8; ++kk) v[kk] = cmul(v[kk], tw1[kk - 1]);
  dft8<1>(v);
  const float scale = 1.0f / (2048.0f * 512.0f);  // 1/N * mean over H*E
#pragma unroll
  for (int m = 0; m < 8; ++m) mv[b * L_ + t + 256 * m] = v[m].x * scale;
}

// ---------- kernel K: batch-mean top-7 + per-batch softmax weights ----------
__global__ __launch_bounds__(256) void topk_kernel(
    const float* __restrict__ mv, int* __restrict__ topk, float* __restrict__ wts) {
  __shared__ float av[2048];
  __shared__ float rv[256];
  __shared__ int   ri[256];
  __shared__ int   sidx[K_];
  int tid = threadIdx.x;
  for (int d = tid; d < 2048; d += 256) {
    float s = 0.f;
#pragma unroll
    for (int b = 0; b < B_; ++b) s += mv[b * L_ + d];
    av[d] = s;
  }
  __syncthreads();
  for (int kk = 0; kk < K_; ++kk) {
    float bv = -INFINITY; int bi = 0;
    for (int d = tid; d < 2048; d += 256) {
      float vv = av[d];
      if (vv > bv) { bv = vv; bi = d; }
    }
    rv[tid] = bv; ri[tid] = bi;
    __syncthreads();
    for (int off = 128; off > 0; off >>= 1) {
      if (tid < off) {
        float v2 = rv[tid + off]; int i2 = ri[tid + off];
        if (v2 > rv[tid] || (v2 == rv[tid] && i2 < ri[tid])) { rv[tid] = v2; ri[tid] = i2; }
      }
      __syncthreads();
    }
    if (tid == 0) { sidx[kk] = ri[0]; av[ri[0]] = -INFINITY; }
    __syncthreads();
  }
  if (tid < K_) topk[tid] = sidx[tid];
  if (tid < B_) {
    float xk[K_], m = -INFINITY;
#pragma unroll
    for (int kk = 0; kk < K_; ++kk) { xk[kk] = mv[tid * L_ + sidx[kk]]; m = fmaxf(m, xk[kk]); }
    float s = 0.f;
#pragma unroll
    for (int kk = 0; kk < K_; ++kk) { xk[kk] = expf(xk[kk] - m); s += xk[kk]; }
#pragma unroll
    for (int kk = 0; kk < K_; ++kk) wts[tid * K_ + kk] = xk[kk] / s;
  }
}

// ---------- kernel G: out[b,t,h,e] = sum_k w[b,k] * v[b,(t+d_k)%L,h,e] ----------
__global__ __launch_bounds__(256) void aggregate_kernel(
    const float4* __restrict__ v4, const int* __restrict__ topk,
    const float* __restrict__ wts, float4* __restrict__ out4) {
  __shared__ int   sidx[K_];
  __shared__ float sw[B_][K_];
  int tid = threadIdx.x;
  if (tid < K_) sidx[tid] = topk[tid];
  if (tid < B_ * K_) sw[tid / K_][tid % K_] = wts[tid];
  __syncthreads();
  int idx = blockIdx.x * 256 + tid;
  int c4  = idx & 127;
  int row = idx >> 7;
  int t   = row & (L_ - 1);
  int b   = row >> 11;
  float4 acc = make_float4(0.f, 0.f, 0.f, 0.f);
#pragma unroll
  for (int kk = 0; kk < K_; ++kk) {
    int s = t + sidx[kk];
    if (s >= L_) s -= L_;
    float w = sw[b][kk];
    float4 val = v4[((size_t)(b * L_ + s) << 7) + c4];
    acc.x += w * val.x; acc.y += w * val.y;
    acc.z += w * val.z; acc.w += w * val.w;
  }
  out4[idx] = acc;
}

extern "C" void kernel_launch(void* const* d_in, const int* in_sizes, int n_in,
                              void* d_out, int out_size, void* d_ws, size_t ws_size,
                              hipStream_t stream) {
  const float* q = (const float*)d_in[0];
  const float* k = (const float*)d_in[1];
  const float* v = (const float*)d_in[2];
  float* out = (float*)d_out;

  char* ws = (char*)d_ws;
  float4* z    = (float4*)(ws + Z_OFF);
  float2* part = (float2*)(ws + PART_OFF);
  float2* S    = (float2*)(ws + S_OFF);
  float*  mv   = (float*) (ws + MV_OFF);
  int*    topk = (int*)   (ws + TK_OFF);
  float*  wts  = (float*) (ws + W_OFF);

  pack_kernel<<<B_ * 64, 512, 0, stream>>>(q, k, z);
  fft_corr_kernel<<<B_ * 128, 256, 2 * RS_ * sizeof(uint2), stream>>>(z, part);
  reduce_S_kernel<<<(B_ * L_) / 256, 256, 0, stream>>>(part, S);
  ifft_kernel<<<B_, 256, 0, stream>>>(S, mv);
  topk_kernel<<<1, 256, 0, stream>>>(mv, topk, wts);
  aggregate_kernel<<<(B_ * L_ * H_ * E_ / 4) / 256, 256, 0, stream>>>(
      (const float4*)v, topk, wts, (float4*)out);
}